// Round 1
// baseline (1246.847 us; speedup 1.0000x reference)
//
#include <hip/hip_runtime.h>
#include <hip/hip_bf16.h>
#include <math.h>

// Problem constants (fixed by reference):
// B=2, S=2048, D=1024, H=16, HD=64, AD=128, M = B*S = 4096
#define TILE 64
#define KT 16
#define LDP 68   // LDS row stride in floats (64 + 4 pad: keeps 16B alignment, breaks bank conflicts)

// ---------------------------------------------------------------------------
// Generic fp32 GEMM: C[m,n] = sum_k A[m,k] * W[n,k] + bias[n]
//   A: [M,K] row-major, W: [N,K] row-major (torch Linear weight layout)
// OUTMODE 0: write out[m*N+n]
// OUTMODE 1: write head layout out[((b*16+h)*2048+s)*64+hd], m=b*2048+s, n=h*64+hd
// GELU: exact-erf gelu on the result (before residual)
// RES : add residual[m*N+n]
// ---------------------------------------------------------------------------
template<int OUTMODE, bool GELU, bool RES>
__global__ __launch_bounds__(256)
void gemm_kernel(const float* __restrict__ A,
                 const float* __restrict__ W,
                 const float* __restrict__ bias,
                 float* __restrict__ out,
                 const float* __restrict__ residual,
                 int M, int N, int K)
{
    __shared__ float As[KT][LDP];
    __shared__ float Ws[KT][LDP];

    const int tid = threadIdx.x;
    const int bm  = blockIdx.x * TILE;
    const int bn  = blockIdx.y * TILE;
    const int lr  = tid >> 2;          // load row within tile 0..63
    const int lk  = (tid & 3) << 2;    // k-offset within tile {0,4,8,12}
    const int ty  = tid >> 4;          // 0..15 -> rows ty*4..+3
    const int tx  = tid & 15;          // 0..15 -> cols tx*4..+3

    float acc[4][4] = {};

    const float* Ap = A + (size_t)(bm + lr) * K + lk;
    const float* Wp = W + (size_t)(bn + lr) * K + lk;

    for (int k0 = 0; k0 < K; k0 += KT) {
        const float4 a4 = *(const float4*)(Ap + k0);
        const float4 w4 = *(const float4*)(Wp + k0);
        __syncthreads();   // previous tile's compute done before overwrite
        As[lk+0][lr] = a4.x; As[lk+1][lr] = a4.y; As[lk+2][lr] = a4.z; As[lk+3][lr] = a4.w;
        Ws[lk+0][lr] = w4.x; Ws[lk+1][lr] = w4.y; Ws[lk+2][lr] = w4.z; Ws[lk+3][lr] = w4.w;
        __syncthreads();
        #pragma unroll
        for (int kk = 0; kk < KT; ++kk) {
            const float4 av = *(const float4*)&As[kk][ty << 2];
            const float4 wv = *(const float4*)&Ws[kk][tx << 2];
            const float a[4] = {av.x, av.y, av.z, av.w};
            const float w[4] = {wv.x, wv.y, wv.z, wv.w};
            #pragma unroll
            for (int i = 0; i < 4; ++i)
                #pragma unroll
                for (int j = 0; j < 4; ++j)
                    acc[i][j] = fmaf(a[i], w[j], acc[i][j]);
        }
    }

    #pragma unroll
    for (int i = 0; i < 4; ++i) {
        const int row = bm + (ty << 2) + i;
        #pragma unroll
        for (int j = 0; j < 4; ++j) {
            const int col = bn + (tx << 2) + j;
            float c = acc[i][j] + bias[col];
            if (GELU) c = 0.5f * c * (1.0f + erff(c * 0.70710678118654752f));
            if (RES)  c += residual[(size_t)row * N + col];
            if (OUTMODE == 1) {
                const int b = row >> 11, s = row & 2047;
                const int h = col >> 6,  hd = col & 63;
                out[((((size_t)b * 16 + h) * 2048 + s) << 6) + hd] = c;
            } else {
                out[(size_t)row * N + col] = c;
            }
        }
    }
}

// ---------------------------------------------------------------------------
// Flash attention, fp32. Q,K,V in [B,H,S,64] layout; ctx written in [B,S,D].
// One block = one (b,h, 64-row q-tile). 256 threads (4 waves).
// Score phase: thread (tr,tc) computes 4x4 scores; PV phase: same 4x4 over HD.
// P is written into the (dead) K-tile LDS buffer to stay under 64KB static LDS.
// ---------------------------------------------------------------------------
__global__ __launch_bounds__(256)
void attn_kernel(const float* __restrict__ Q,
                 const float* __restrict__ K,
                 const float* __restrict__ V,
                 float* __restrict__ ctx)
{
    __shared__ float Qs[64][LDP];
    __shared__ float Ks[64][LDP];   // holds K-tile, then reused for P
    __shared__ float Vs[64][LDP];

    const int tid = threadIdx.x;
    const int bh  = blockIdx.y;           // b*16 + h
    const int q0  = blockIdx.x << 6;
    const int lr  = tid >> 2;             // load row 0..63
    const int lc  = (tid & 3) << 4;       // load col base {0,16,32,48}
    const int tr  = tid >> 4;             // 0..15 -> rows tr*4..+3
    const int tc  = tid & 15;             // 0..15 -> cols tc*4..+3

    const float* Qb = Q + (size_t)bh * (2048 * 64);
    const float* Kb = K + (size_t)bh * (2048 * 64);
    const float* Vb = V + (size_t)bh * (2048 * 64);

    // load Q tile (64x64)
    #pragma unroll
    for (int j = 0; j < 16; j += 4) {
        const float4 v4 = *(const float4*)(Qb + (size_t)(q0 + lr) * 64 + lc + j);
        *(float4*)&Qs[lr][lc + j] = v4;
    }

    float m[4], l[4], accO[4][4];
    #pragma unroll
    for (int i = 0; i < 4; ++i) {
        m[i] = -1e30f; l[i] = 0.f;
        #pragma unroll
        for (int j = 0; j < 4; ++j) accO[i][j] = 0.f;
    }

    for (int kt = 0; kt < 2048; kt += 64) {
        // issue global loads for K,V tiles early
        float4 k4[4], v4[4];
        #pragma unroll
        for (int j = 0; j < 4; ++j) {
            k4[j] = *(const float4*)(Kb + (size_t)(kt + lr) * 64 + lc + j * 4);
            v4[j] = *(const float4*)(Vb + (size_t)(kt + lr) * 64 + lc + j * 4);
        }
        __syncthreads();   // previous iteration's PV reads done
        #pragma unroll
        for (int j = 0; j < 4; ++j) {
            *(float4*)&Ks[lr][lc + j * 4] = k4[j];
            *(float4*)&Vs[lr][lc + j * 4] = v4[j];
        }
        __syncthreads();

        // --- scores: s[i][j] = (Q[tr*4+i] . K[tc*4+j]) * 0.125 ---
        float s[4][4] = {};
        #pragma unroll
        for (int d = 0; d < 64; d += 4) {
            float4 qa[4], kb[4];
            #pragma unroll
            for (int i = 0; i < 4; ++i) qa[i] = *(const float4*)&Qs[(tr << 2) + i][d];
            #pragma unroll
            for (int j = 0; j < 4; ++j) kb[j] = *(const float4*)&Ks[(tc << 2) + j][d];
            #pragma unroll
            for (int i = 0; i < 4; ++i)
                #pragma unroll
                for (int j = 0; j < 4; ++j)
                    s[i][j] += qa[i].x*kb[j].x + qa[i].y*kb[j].y
                             + qa[i].z*kb[j].z + qa[i].w*kb[j].w;
        }

        // --- online softmax over the 16-lane row group ---
        float resc[4];
        #pragma unroll
        for (int i = 0; i < 4; ++i) {
            #pragma unroll
            for (int j = 0; j < 4; ++j) s[i][j] *= 0.125f;
            float rm = fmaxf(fmaxf(s[i][0], s[i][1]), fmaxf(s[i][2], s[i][3]));
            rm = fmaxf(rm, __shfl_xor(rm, 1));
            rm = fmaxf(rm, __shfl_xor(rm, 2));
            rm = fmaxf(rm, __shfl_xor(rm, 4));
            rm = fmaxf(rm, __shfl_xor(rm, 8));
            const float mnew = fmaxf(m[i], rm);
            float rs = 0.f;
            #pragma unroll
            for (int j = 0; j < 4; ++j) {
                const float p = __expf(s[i][j] - mnew);
                s[i][j] = p;
                rs += p;
            }
            rs += __shfl_xor(rs, 1);
            rs += __shfl_xor(rs, 2);
            rs += __shfl_xor(rs, 4);
            rs += __shfl_xor(rs, 8);
            resc[i] = __expf(m[i] - mnew);
            l[i] = l[i] * resc[i] + rs;
            m[i] = mnew;
        }

        __syncthreads();   // all score-phase reads of Ks done
        // write P into the dead K buffer
        #pragma unroll
        for (int i = 0; i < 4; ++i)
            #pragma unroll
            for (int j = 0; j < 4; ++j)
                Ks[(tr << 2) + i][(tc << 2) + j] = s[i][j];
        __syncthreads();

        // --- PV: accO[i][j] = accO*resc + sum_k P[row,k] * V[k, tc*4+j] ---
        #pragma unroll
        for (int i = 0; i < 4; ++i)
            #pragma unroll
            for (int j = 0; j < 4; ++j)
                accO[i][j] *= resc[i];
        for (int k = 0; k < 64; ++k) {
            const float4 vv = *(const float4*)&Vs[k][tc << 2];
            #pragma unroll
            for (int i = 0; i < 4; ++i) {
                const float p = Ks[(tr << 2) + i][k];
                accO[i][0] = fmaf(p, vv.x, accO[i][0]);
                accO[i][1] = fmaf(p, vv.y, accO[i][1]);
                accO[i][2] = fmaf(p, vv.z, accO[i][2]);
                accO[i][3] = fmaf(p, vv.w, accO[i][3]);
            }
        }
    }

    // write ctx in [B,S,D] layout: ctx[b, q0+row, h*64 + d]
    const int b = bh >> 4, h = bh & 15;
    #pragma unroll
    for (int i = 0; i < 4; ++i) {
        const int row = q0 + (tr << 2) + i;
        const float inv = 1.0f / l[i];
        float4 o = make_float4(accO[i][0]*inv, accO[i][1]*inv, accO[i][2]*inv, accO[i][3]*inv);
        *(float4*)&ctx[((size_t)b * 2048 + row) * 1024 + (h << 6) + (tc << 2)] = o;
    }
}

// ---------------------------------------------------------------------------
extern "C" void kernel_launch(void* const* d_in, const int* in_sizes, int n_in,
                              void* d_out, int out_size, void* d_ws, size_t ws_size,
                              hipStream_t stream) {
    const float* q   = (const float*)d_in[0];
    const float* k   = (const float*)d_in[1];
    const float* v   = (const float*)d_in[2];
    const float* Wq  = (const float*)d_in[3];
    const float* bq  = (const float*)d_in[4];
    const float* Wk  = (const float*)d_in[5];
    const float* bk  = (const float*)d_in[6];
    const float* Wv  = (const float*)d_in[7];
    const float* bv  = (const float*)d_in[8];
    const float* Wo  = (const float*)d_in[9];
    const float* bo  = (const float*)d_in[10];
    const float* Wad = (const float*)d_in[11];
    const float* bad = (const float*)d_in[12];
    const float* Wau = (const float*)d_in[13];
    const float* bau = (const float*)d_in[14];

    const int M = 4096, D = 1024, AD = 128;
    const size_t SZ = (size_t)M * D;   // 4,194,304 floats

    float* ws   = (float*)d_ws;
    float* Qh   = ws;            // [B,H,S,64]
    float* Kh   = Qh  + SZ;
    float* Vh   = Kh  + SZ;
    float* ctx  = Vh  + SZ;      // [B,S,D]
    float* aout = ctx + SZ;      // [B,S,D]  (attention output proj, kept for residual)
    float* a1   = aout + SZ;     // [M,AD]   adapter hidden

    const dim3 blk(256);

    // Q/K/V projections -> head layout
    gemm_kernel<1,false,false><<<dim3(M/TILE, D/TILE), blk, 0, stream>>>(q, Wq, bq, Qh, nullptr, M, D, D);
    gemm_kernel<1,false,false><<<dim3(M/TILE, D/TILE), blk, 0, stream>>>(k, Wk, bk, Kh, nullptr, M, D, D);
    gemm_kernel<1,false,false><<<dim3(M/TILE, D/TILE), blk, 0, stream>>>(v, Wv, bv, Vh, nullptr, M, D, D);

    // attention
    attn_kernel<<<dim3(2048/64, 32), blk, 0, stream>>>(Qh, Kh, Vh, ctx);

    // output projection (kept in ws for residual + adapter input)
    gemm_kernel<0,false,false><<<dim3(M/TILE, D/TILE), blk, 0, stream>>>(ctx, Wo, bo, aout, nullptr, M, D, D);

    // adapter down + exact GELU
    gemm_kernel<0,true,false><<<dim3(M/TILE, AD/TILE), blk, 0, stream>>>(aout, Wad, bad, a1, nullptr, M, AD, D);

    // adapter up + residual -> final output
    gemm_kernel<0,false,true><<<dim3(M/TILE, D/TILE), blk, 0, stream>>>(a1, Wau, bau, (float*)d_out, aout, M, D, AD);
}

// Round 2
// 327.694 us; speedup vs baseline: 3.8049x; 3.8049x over previous
//
#include <hip/hip_runtime.h>
#include <hip/hip_bf16.h>
#include <math.h>

// B=2, S=2048, D=1024, H=16, HD=64, AD=128, M=B*S=4096
typedef __attribute__((ext_vector_type(8))) short short8;
typedef __attribute__((ext_vector_type(4))) float f32x4;

#define MFMA16(a, b, c) __builtin_amdgcn_mfma_f32_16x16x32_bf16((a), (b), (c), 0, 0, 0)

__device__ __forceinline__ unsigned short f2bf(float f) {
    unsigned u = __float_as_uint(f);
    unsigned r = (u + 0x7fffu + ((u >> 16) & 1u)) >> 16;   // RNE
    return (unsigned short)r;
}

#define GLD_LDS16(g, s) \
    __builtin_amdgcn_global_load_lds((const __attribute__((address_space(1))) void*)(g), \
                                     (__attribute__((address_space(3))) void*)(s), 16, 0, 0)

// ---------------------------------------------------------------------------
// fp32 -> bf16 batched conversion (9 tensors), grid-stride over float4 groups
// ---------------------------------------------------------------------------
struct CvtJobs {
    const float* src[9];
    unsigned short* dst[9];
    int n[9];          // element counts, all multiples of 4
};

__global__ __launch_bounds__(256)
void convert_kernel(CvtJobs j, long long total4) {
    long long i4 = (long long)blockIdx.x * blockDim.x + threadIdx.x;
    if (i4 >= total4) return;
    long long rem = i4 * 4;
    int job = 0;
    while (job < 9 && rem >= j.n[job]) { rem -= j.n[job]; ++job; }
    if (job >= 9) return;
    const float4 v = *(const float4*)(j.src[job] + rem);
    ushort4 o;
    o.x = f2bf(v.x); o.y = f2bf(v.y); o.z = f2bf(v.z); o.w = f2bf(v.w);
    *(ushort4*)(j.dst[job] + rem) = o;
}

// ---------------------------------------------------------------------------
// bf16 MFMA GEMM, m97-structure: 128x128 tile, BK=32, 4 waves, each wave 64x64.
// C[m,n] = sum_k A[m,k]*Wt[n,k] + bias[n]   (A:[M,K] bf16, Wt:[N,K] bf16)
// MODE 0: bf16 out, head layout [b,h,s,64]
// MODE 1: bf16 out, TRANSPOSED head layout [b,h,hd,s]   (for V)
// MODE 2: fp32 out0 + bf16 out1 (both [M,N])            (O-proj)
// MODE 3: exact-erf GELU -> bf16 out0                   (adapter down)
// MODE 4: + fp32 residual(out1) -> fp32 out0            (adapter up)
// ---------------------------------------------------------------------------
template<int MODE>
__global__ __launch_bounds__(256)
void gemm_bf16(const unsigned short* __restrict__ A,
               const unsigned short* __restrict__ Wt,
               const float* __restrict__ bias,
               void* __restrict__ out0,
               void* __restrict__ out1,
               int M, int N, int K)
{
    __shared__ unsigned short As[128 * 32];
    __shared__ unsigned short Bs[128 * 32];

    const int tid = threadIdx.x;
    const int w = tid >> 6, l = tid & 63;
    const int lr = l & 15, lg = l >> 4;
    const int m0 = blockIdx.x * 128, n0 = blockIdx.y * 128;

    f32x4 acc[4][4] = {};

    for (int k0 = 0; k0 < K; k0 += 32) {
        __syncthreads();                      // previous tile's reads complete
        #pragma unroll
        for (int c = 0; c < 2; ++c) {
            const int idx = c * 256 + tid;    // 16B chunk id, 512 per 8KB tile
            const int row = idx >> 2, ch = idx & 3;
            const unsigned short* ga = A  + (size_t)(m0 + row) * K + k0 + ch * 8;
            const unsigned short* gb = Wt + (size_t)(n0 + row) * K + k0 + ch * 8;
            GLD_LDS16(ga, As + (c * 256 + w * 64) * 8);
            GLD_LDS16(gb, Bs + (c * 256 + w * 64) * 8);
        }
        __syncthreads();                      // drains vmcnt(0) then barrier

        short8 af[4], bf[4];
        #pragma unroll
        for (int i = 0; i < 4; ++i)
            af[i] = *(const short8*)(As + (((w >> 1) * 64 + i * 16 + lr) * 32 + lg * 8));
        #pragma unroll
        for (int j = 0; j < 4; ++j)
            bf[j] = *(const short8*)(Bs + (((w & 1) * 64 + j * 16 + lr) * 32 + lg * 8));
        #pragma unroll
        for (int i = 0; i < 4; ++i)
            #pragma unroll
            for (int j = 0; j < 4; ++j)
                acc[i][j] = MFMA16(af[i], bf[j], acc[i][j]);
    }

    #pragma unroll
    for (int i = 0; i < 4; ++i) {
        #pragma unroll
        for (int j = 0; j < 4; ++j) {
            #pragma unroll
            for (int r = 0; r < 4; ++r) {
                const int row = m0 + (w >> 1) * 64 + i * 16 + lg * 4 + r;
                const int col = n0 + (w & 1) * 64 + j * 16 + lr;
                float c = acc[i][j][r] + bias[col];
                if (MODE == 0) {
                    const int b = row >> 11, s = row & 2047, h = col >> 6, hd = col & 63;
                    ((unsigned short*)out0)[((((size_t)(b * 16 + h)) * 2048 + s) << 6) + hd] = f2bf(c);
                } else if (MODE == 1) {
                    const int b = row >> 11, s = row & 2047, h = col >> 6, hd = col & 63;
                    ((unsigned short*)out0)[((((size_t)(b * 16 + h)) * 64 + hd) << 11) + s] = f2bf(c);
                } else if (MODE == 2) {
                    ((float*)out0)[(size_t)row * N + col] = c;
                    ((unsigned short*)out1)[(size_t)row * N + col] = f2bf(c);
                } else if (MODE == 3) {
                    const float g = 0.5f * c * (1.0f + erff(c * 0.70710678118654752f));
                    ((unsigned short*)out0)[(size_t)row * N + col] = f2bf(g);
                } else {
                    ((float*)out0)[(size_t)row * N + col] =
                        c + ((const float*)out1)[(size_t)row * N + col];
                }
            }
        }
    }
}

// ---------------------------------------------------------------------------
// Flash attention, bf16 MFMA. Qh,Kh: [B,H,S,64] bf16; Vt: [B,H,64,S] bf16.
// ctx out: [B,S,D] bf16. Block = 64 q-rows of one (b,h); 4 waves x 16 rows.
// LDS rows padded to 72 elems (144B = 9x16B) -> <=2-way bank aliasing (free).
// P is round-tripped through the dead K buffer.
// ---------------------------------------------------------------------------
__global__ __launch_bounds__(256)
void attn_mfma(const unsigned short* __restrict__ Qh,
               const unsigned short* __restrict__ Kh,
               const unsigned short* __restrict__ Vt,
               unsigned short* __restrict__ ctx)
{
    __shared__ unsigned short Qs[64 * 72];
    __shared__ unsigned short Ks[64 * 72];   // K tile, then P
    __shared__ unsigned short Vs[64 * 72];   // Vt tile [d][k]

    const int tid = threadIdx.x;
    const int w = tid >> 6, l = tid & 63;
    const int lr = l & 15, lg = l >> 4;
    const int bh = blockIdx.y;
    const int q0 = blockIdx.x << 6;

    const unsigned short* Qb = Qh + (size_t)bh * 131072;
    const unsigned short* Kb = Kh + (size_t)bh * 131072;
    const unsigned short* Vb = Vt + (size_t)bh * 131072;

    // stage Q tile (64x64)
    #pragma unroll
    for (int c = 0; c < 2; ++c) {
        const int idx = c * 256 + tid;
        const int row = idx >> 3, ch = idx & 7;
        const int4 v = *(const int4*)(Qb + (size_t)(q0 + row) * 64 + ch * 8);
        *(int4*)(Qs + row * 72 + ch * 8) = v;
    }
    __syncthreads();

    // Q fragments are stationary: rows w*16 + lr, k-chunks lg*8 (+32)
    short8 qf[2];
    qf[0] = *(const short8*)(Qs + (w * 16 + lr) * 72 + lg * 8);
    qf[1] = *(const short8*)(Qs + (w * 16 + lr) * 72 + 32 + lg * 8);

    float mrow[4], lrow[4];
    f32x4 accO[4] = {};
    #pragma unroll
    for (int r = 0; r < 4; ++r) { mrow[r] = -1e30f; lrow[r] = 0.f; }

    for (int kt = 0; kt < 2048; kt += 64) {
        // issue global loads early (regs), overlap with prev PV
        int4 kreg[2], vreg[2];
        #pragma unroll
        for (int c = 0; c < 2; ++c) {
            const int idx = c * 256 + tid;
            const int row = idx >> 3, ch = idx & 7;
            kreg[c] = *(const int4*)(Kb + (size_t)(kt + row) * 64 + ch * 8);
            vreg[c] = *(const int4*)(Vb + (size_t)row * 2048 + kt + ch * 8);
        }
        __syncthreads();                       // prev PV reads of Ks/Vs done
        #pragma unroll
        for (int c = 0; c < 2; ++c) {
            const int idx = c * 256 + tid;
            const int row = idx >> 3, ch = idx & 7;
            *(int4*)(Ks + row * 72 + ch * 8) = kreg[c];
            *(int4*)(Vs + row * 72 + ch * 8) = vreg[c];
        }
        __syncthreads();

        // --- QK^T: sf[n] = Q[16x64] . K[16n..16n+15]^T ---
        f32x4 sf[4] = {};
        #pragma unroll
        for (int n = 0; n < 4; ++n) {
            const short8 kf0 = *(const short8*)(Ks + (n * 16 + lr) * 72 + lg * 8);
            const short8 kf1 = *(const short8*)(Ks + (n * 16 + lr) * 72 + 32 + lg * 8);
            sf[n] = MFMA16(qf[0], kf0, sf[n]);
            sf[n] = MFMA16(qf[1], kf1, sf[n]);
        }

        // --- online softmax: row r = q-local lg*4+r, col = n*16+lr ---
        float resc[4];
        unsigned short pb[4][4];
        #pragma unroll
        for (int r = 0; r < 4; ++r) {
            float s0 = sf[0][r] * 0.125f, s1 = sf[1][r] * 0.125f;
            float s2 = sf[2][r] * 0.125f, s3 = sf[3][r] * 0.125f;
            float rm = fmaxf(fmaxf(s0, s1), fmaxf(s2, s3));
            rm = fmaxf(rm, __shfl_xor(rm, 1));
            rm = fmaxf(rm, __shfl_xor(rm, 2));
            rm = fmaxf(rm, __shfl_xor(rm, 4));
            rm = fmaxf(rm, __shfl_xor(rm, 8));
            const float mnew = fmaxf(mrow[r], rm);
            const float p0 = __expf(s0 - mnew), p1 = __expf(s1 - mnew);
            const float p2 = __expf(s2 - mnew), p3 = __expf(s3 - mnew);
            float rs = p0 + p1 + p2 + p3;
            rs += __shfl_xor(rs, 1);
            rs += __shfl_xor(rs, 2);
            rs += __shfl_xor(rs, 4);
            rs += __shfl_xor(rs, 8);
            resc[r] = __expf(mrow[r] - mnew);
            lrow[r] = lrow[r] * resc[r] + rs;
            mrow[r] = mnew;
            pb[r][0] = f2bf(p0); pb[r][1] = f2bf(p1);
            pb[r][2] = f2bf(p2); pb[r][3] = f2bf(p3);
        }

        __syncthreads();                       // all QK^T reads of Ks done
        #pragma unroll
        for (int r = 0; r < 4; ++r)
            #pragma unroll
            for (int n = 0; n < 4; ++n)
                Ks[(w * 16 + lg * 4 + r) * 72 + n * 16 + lr] = pb[r][n];
        __syncthreads();                       // P visible

        // --- PV: accO[n] = accO[n]*resc + P[16x64] . V[64 x 16n..] ---
        #pragma unroll
        for (int n = 0; n < 4; ++n)
            #pragma unroll
            for (int r = 0; r < 4; ++r)
                accO[n][r] *= resc[r];

        const short8 pf0 = *(const short8*)(Ks + (w * 16 + lr) * 72 + lg * 8);
        const short8 pf1 = *(const short8*)(Ks + (w * 16 + lr) * 72 + 32 + lg * 8);
        #pragma unroll
        for (int n = 0; n < 4; ++n) {
            const short8 vf0 = *(const short8*)(Vs + (n * 16 + lr) * 72 + lg * 8);
            const short8 vf1 = *(const short8*)(Vs + (n * 16 + lr) * 72 + 32 + lg * 8);
            accO[n] = MFMA16(pf0, vf0, accO[n]);
            accO[n] = MFMA16(pf1, vf1, accO[n]);
        }
    }

    // write ctx [B,S,D] bf16
    const int b = bh >> 4, h = bh & 15;
    #pragma unroll
    for (int r = 0; r < 4; ++r) {
        const float inv = 1.0f / lrow[r];
        const int srow = q0 + w * 16 + lg * 4 + r;
        const size_t base = ((size_t)b * 2048 + srow) * 1024 + h * 64;
        #pragma unroll
        for (int n = 0; n < 4; ++n)
            ctx[base + n * 16 + lr] = f2bf(accO[n][r] * inv);
    }
}

// ---------------------------------------------------------------------------
extern "C" void kernel_launch(void* const* d_in, const int* in_sizes, int n_in,
                              void* d_out, int out_size, void* d_ws, size_t ws_size,
                              hipStream_t stream) {
    const float* q   = (const float*)d_in[0];
    const float* k   = (const float*)d_in[1];
    const float* v   = (const float*)d_in[2];
    const float* Wq  = (const float*)d_in[3];
    const float* bq  = (const float*)d_in[4];
    const float* Wk  = (const float*)d_in[5];
    const float* bk  = (const float*)d_in[6];
    const float* Wv  = (const float*)d_in[7];
    const float* bv  = (const float*)d_in[8];
    const float* Wo  = (const float*)d_in[9];
    const float* bo  = (const float*)d_in[10];
    const float* Wad = (const float*)d_in[11];
    const float* bad = (const float*)d_in[12];
    const float* Wau = (const float*)d_in[13];
    const float* bau = (const float*)d_in[14];

    const int M = 4096, D = 1024, AD = 128;
    const size_t SZ = (size_t)M * D;           // 4,194,304

    // ws layout (bytes)
    char* p = (char*)d_ws;
    size_t off = 0;
    auto alloc = [&](size_t bytes) { void* r = p + off; off = (off + bytes + 255) & ~(size_t)255; return r; };
    unsigned short* xq   = (unsigned short*)alloc(SZ * 2);
    unsigned short* xk   = (unsigned short*)alloc(SZ * 2);
    unsigned short* xv   = (unsigned short*)alloc(SZ * 2);
    unsigned short* Wqb  = (unsigned short*)alloc((size_t)D * D * 2);
    unsigned short* Wkb  = (unsigned short*)alloc((size_t)D * D * 2);
    unsigned short* Wvb  = (unsigned short*)alloc((size_t)D * D * 2);
    unsigned short* Wob  = (unsigned short*)alloc((size_t)D * D * 2);
    unsigned short* Wadb = (unsigned short*)alloc((size_t)AD * D * 2);
    unsigned short* Waub = (unsigned short*)alloc((size_t)D * AD * 2);
    unsigned short* Qh   = (unsigned short*)alloc(SZ * 2);   // [B,H,S,64]
    unsigned short* Kh   = (unsigned short*)alloc(SZ * 2);   // [B,H,S,64]
    unsigned short* Vt   = (unsigned short*)alloc(SZ * 2);   // [B,H,64,S]
    unsigned short* ctx  = (unsigned short*)alloc(SZ * 2);   // [M,D] bf16
    float*          outp = (float*)alloc(SZ * 4);            // O-proj fp32
    unsigned short* outb = (unsigned short*)alloc(SZ * 2);   // O-proj bf16
    unsigned short* a1   = (unsigned short*)alloc((size_t)M * AD * 2);

    // 1. convert fp32 -> bf16
    CvtJobs j;
    j.src[0] = q;   j.dst[0] = xq;   j.n[0] = (int)SZ;
    j.src[1] = k;   j.dst[1] = xk;   j.n[1] = (int)SZ;
    j.src[2] = v;   j.dst[2] = xv;   j.n[2] = (int)SZ;
    j.src[3] = Wq;  j.dst[3] = Wqb;  j.n[3] = D * D;
    j.src[4] = Wk;  j.dst[4] = Wkb;  j.n[4] = D * D;
    j.src[5] = Wv;  j.dst[5] = Wvb;  j.n[5] = D * D;
    j.src[6] = Wo;  j.dst[6] = Wob;  j.n[6] = D * D;
    j.src[7] = Wad; j.dst[7] = Wadb; j.n[7] = AD * D;
    j.src[8] = Wau; j.dst[8] = Waub; j.n[8] = D * AD;
    long long total = 3LL * SZ + 4LL * D * D + 2LL * AD * D;
    long long total4 = total / 4;
    convert_kernel<<<dim3((unsigned)((total4 + 255) / 256)), dim3(256), 0, stream>>>(j, total4);

    const dim3 blk(256);
    // 2-4. projections
    gemm_bf16<0><<<dim3(M / 128, D / 128), blk, 0, stream>>>(xq, Wqb, bq, Qh, nullptr, M, D, D);
    gemm_bf16<0><<<dim3(M / 128, D / 128), blk, 0, stream>>>(xk, Wkb, bk, Kh, nullptr, M, D, D);
    gemm_bf16<1><<<dim3(M / 128, D / 128), blk, 0, stream>>>(xv, Wvb, bv, Vt, nullptr, M, D, D);
    // 5. attention
    attn_mfma<<<dim3(2048 / 64, 32), blk, 0, stream>>>(Qh, Kh, Vt, ctx);
    // 6. O-proj (fp32 + bf16 copy)
    gemm_bf16<2><<<dim3(M / 128, D / 128), blk, 0, stream>>>(ctx, Wob, bo, outp, outb, M, D, D);
    // 7. adapter down + GELU
    gemm_bf16<3><<<dim3(M / 128, AD / 128), blk, 0, stream>>>(outb, Wadb, bad, a1, nullptr, M, AD, D);
    // 8. adapter up + residual
    gemm_bf16<4><<<dim3(M / 128, D / 128), blk, 0, stream>>>(a1, Waub, bau, d_out, outp, M, D, AD);
}

// Round 3
// 263.286 us; speedup vs baseline: 4.7357x; 1.2446x over previous
//
#include <hip/hip_runtime.h>
#include <hip/hip_bf16.h>
#include <math.h>

// B=2, S=2048, D=1024, H=16, HD=64, AD=128, M=B*S=4096
typedef __attribute__((ext_vector_type(8))) short short8;
typedef __attribute__((ext_vector_type(4))) float f32x4;

#define MFMA16(a, b, c) __builtin_amdgcn_mfma_f32_16x16x32_bf16((a), (b), (c), 0, 0, 0)

__device__ __forceinline__ unsigned short f2bf(float f) {
    union { __hip_bfloat16 b; unsigned short u; } cv;
    cv.b = __float2bfloat16(f);   // hardware RNE cvt on gfx950
    return cv.u;
}

#define GLD_LDS16(g, s) \
    __builtin_amdgcn_global_load_lds((const __attribute__((address_space(1))) void*)(g), \
                                     (__attribute__((address_space(3))) void*)(s), 16, 0, 0)

// 1/sqrt(HD) folded into Wq (and bq via bscale) at conversion time
#define QSCALE 0.125f

// ---------------------------------------------------------------------------
// fp32 -> bf16 batched conversion (9 tensors) with per-job scale
// ---------------------------------------------------------------------------
struct CvtJobs {
    const float* src[9];
    unsigned short* dst[9];
    float scale[9];
    int n[9];          // element counts, all multiples of 4
};

__global__ __launch_bounds__(256)
void convert_kernel(CvtJobs j, long long total4) {
    long long i4 = (long long)blockIdx.x * blockDim.x + threadIdx.x;
    if (i4 >= total4) return;
    long long rem = i4 * 4;
    int job = 0;
    while (job < 9 && rem >= j.n[job]) { rem -= j.n[job]; ++job; }
    if (job >= 9) return;
    const float sc = j.scale[job];
    const float4 v = *(const float4*)(j.src[job] + rem);
    ushort4 o;
    o.x = f2bf(v.x * sc); o.y = f2bf(v.y * sc);
    o.z = f2bf(v.z * sc); o.w = f2bf(v.w * sc);
    *(ushort4*)(j.dst[job] + rem) = o;
}

// ---------------------------------------------------------------------------
// bf16 MFMA GEMM, 128x128 tile, BK=32, 4 waves (each 64x64).
// C[m,n] = sum_k A[m,k]*Wt[n,k] + bias[n]*bscale
// MODE 0: bf16 out, head layout [b,h,s,64]
// MODE 1: bf16 out, transposed head layout [b,h,hd,s]   (V)
// MODE 2: fp32 out0 + bf16 out1 (both [M,N])            (O-proj)
// MODE 4: + fp32 residual(out1) -> fp32 out0            (adapter up)
// ---------------------------------------------------------------------------
template<int MODE>
__global__ __launch_bounds__(256)
void gemm_bf16(const unsigned short* __restrict__ A,
               const unsigned short* __restrict__ Wt,
               const float* __restrict__ bias,
               void* __restrict__ out0,
               void* __restrict__ out1,
               int M, int N, int K, float bscale)
{
    __shared__ unsigned short As[128 * 32];
    __shared__ unsigned short Bs[128 * 32];

    const int tid = threadIdx.x;
    const int w = tid >> 6, l = tid & 63;
    const int lr = l & 15, lg = l >> 4;
    const int m0 = blockIdx.x * 128, n0 = blockIdx.y * 128;

    f32x4 acc[4][4] = {};

    for (int k0 = 0; k0 < K; k0 += 32) {
        __syncthreads();
        #pragma unroll
        for (int c = 0; c < 2; ++c) {
            const int idx = c * 256 + tid;
            const int row = idx >> 2, ch = idx & 3;
            const unsigned short* ga = A  + (size_t)(m0 + row) * K + k0 + ch * 8;
            const unsigned short* gb = Wt + (size_t)(n0 + row) * K + k0 + ch * 8;
            GLD_LDS16(ga, As + (c * 256 + w * 64) * 8);
            GLD_LDS16(gb, Bs + (c * 256 + w * 64) * 8);
        }
        __syncthreads();

        short8 af[4], bf[4];
        #pragma unroll
        for (int i = 0; i < 4; ++i)
            af[i] = *(const short8*)(As + (((w >> 1) * 64 + i * 16 + lr) * 32 + lg * 8));
        #pragma unroll
        for (int j = 0; j < 4; ++j)
            bf[j] = *(const short8*)(Bs + (((w & 1) * 64 + j * 16 + lr) * 32 + lg * 8));
        #pragma unroll
        for (int i = 0; i < 4; ++i)
            #pragma unroll
            for (int j = 0; j < 4; ++j)
                acc[i][j] = MFMA16(af[i], bf[j], acc[i][j]);
    }

    #pragma unroll
    for (int i = 0; i < 4; ++i) {
        #pragma unroll
        for (int j = 0; j < 4; ++j) {
            #pragma unroll
            for (int r = 0; r < 4; ++r) {
                const int row = m0 + (w >> 1) * 64 + i * 16 + lg * 4 + r;
                const int col = n0 + (w & 1) * 64 + j * 16 + lr;
                float c = acc[i][j][r] + bias[col] * bscale;
                if (MODE == 0) {
                    const int b = row >> 11, s = row & 2047, h = col >> 6, hd = col & 63;
                    ((unsigned short*)out0)[((((size_t)(b * 16 + h)) * 2048 + s) << 6) + hd] = f2bf(c);
                } else if (MODE == 1) {
                    const int b = row >> 11, s = row & 2047, h = col >> 6, hd = col & 63;
                    ((unsigned short*)out0)[((((size_t)(b * 16 + h)) * 64 + hd) << 11) + s] = f2bf(c);
                } else if (MODE == 2) {
                    ((float*)out0)[(size_t)row * N + col] = c;
                    ((unsigned short*)out1)[(size_t)row * N + col] = f2bf(c);
                } else {
                    ((float*)out0)[(size_t)row * N + col] =
                        c + ((const float*)out1)[(size_t)row * N + col];
                }
            }
        }
    }
}

// ---------------------------------------------------------------------------
// 64x64-tile GEMM + exact GELU (adapter down, N=128 -> 128 blocks)
// 4 waves in 2x2, each wave 32x32 output.
// ---------------------------------------------------------------------------
__global__ __launch_bounds__(256)
void gemm64_gelu(const unsigned short* __restrict__ A,
                 const unsigned short* __restrict__ Wt,
                 const float* __restrict__ bias,
                 unsigned short* __restrict__ out,
                 int M, int N, int K)
{
    __shared__ unsigned short As[64 * 32];
    __shared__ unsigned short Bs[64 * 32];

    const int tid = threadIdx.x;
    const int w = tid >> 6, l = tid & 63;
    const int lr = l & 15, lg = l >> 4;
    const int wr = w >> 1, wc = w & 1;
    const int m0 = blockIdx.x * 64, n0 = blockIdx.y * 64;

    f32x4 acc[2][2] = {};

    for (int k0 = 0; k0 < K; k0 += 32) {
        const int row = tid >> 2, ch = tid & 3;
        __syncthreads();
        GLD_LDS16(A  + (size_t)(m0 + row) * K + k0 + ch * 8, As + (w * 64) * 8);
        GLD_LDS16(Wt + (size_t)(n0 + row) * K + k0 + ch * 8, Bs + (w * 64) * 8);
        __syncthreads();

        short8 af[2], bf[2];
        #pragma unroll
        for (int i = 0; i < 2; ++i)
            af[i] = *(const short8*)(As + ((wr * 32 + i * 16 + lr) * 32 + lg * 8));
        #pragma unroll
        for (int j = 0; j < 2; ++j)
            bf[j] = *(const short8*)(Bs + ((wc * 32 + j * 16 + lr) * 32 + lg * 8));
        #pragma unroll
        for (int i = 0; i < 2; ++i)
            #pragma unroll
            for (int j = 0; j < 2; ++j)
                acc[i][j] = MFMA16(af[i], bf[j], acc[i][j]);
    }

    #pragma unroll
    for (int i = 0; i < 2; ++i)
        #pragma unroll
        for (int j = 0; j < 2; ++j)
            #pragma unroll
            for (int r = 0; r < 4; ++r) {
                const int row = m0 + wr * 32 + i * 16 + lg * 4 + r;
                const int col = n0 + wc * 32 + j * 16 + lr;
                float c = acc[i][j][r] + bias[col];
                const float g = 0.5f * c * (1.0f + erff(c * 0.70710678118654752f));
                out[(size_t)row * N + col] = f2bf(g);
            }
}

// ---------------------------------------------------------------------------
// Flash attention, bf16 MFMA. Qh,Kh: [B,H,S,64]; Vt: [B,H,64,S] (bf16).
// Block = 128 q-rows of one (b,h); 4 waves x 32 rows (2 m-tiles of 16).
// KV tile = 64. Scale 1/sqrt(HD) pre-folded into Q. LDS stride 72 (2-way max).
// P (128x64) reuses the dead Q-staging buffer. Defer-max (THR=8) + deferred
// cross-lane l-reduction (once at end).
// ---------------------------------------------------------------------------
__global__ __launch_bounds__(256)
void attn_mfma(const unsigned short* __restrict__ Qh,
               const unsigned short* __restrict__ Kh,
               const unsigned short* __restrict__ Vt,
               unsigned short* __restrict__ ctx)
{
    __shared__ unsigned short Qs[128 * 72];   // Q tile, then P
    __shared__ unsigned short Ks[64 * 72];
    __shared__ unsigned short Vs[64 * 72];

    const int tid = threadIdx.x;
    const int w = tid >> 6, l = tid & 63;
    const int lr = l & 15, lg = l >> 4;
    const int bh = blockIdx.y;
    const int q0 = blockIdx.x << 7;           // 128 q-rows per block

    const unsigned short* Qb = Qh + (size_t)bh * 131072;
    const unsigned short* Kb = Kh + (size_t)bh * 131072;
    const unsigned short* Vb = Vt + (size_t)bh * 131072;

    // stage Q tile (128x64): 1024 16B-chunks, 4 per thread
    #pragma unroll
    for (int c = 0; c < 4; ++c) {
        const int idx = c * 256 + tid;
        const int row = idx >> 3, ch = idx & 7;
        *(int4*)(Qs + row * 72 + ch * 8) =
            *(const int4*)(Qb + (size_t)(q0 + row) * 64 + ch * 8);
    }
    __syncthreads();

    // stationary Q fragments: wave w rows w*32+mm*16+lr, k-chunks c*32+lg*8
    short8 qf[2][2];
    #pragma unroll
    for (int mm = 0; mm < 2; ++mm)
        #pragma unroll
        for (int c = 0; c < 2; ++c)
            qf[mm][c] = *(const short8*)(Qs + (w * 32 + mm * 16 + lr) * 72 + c * 32 + lg * 8);

    float mrow[2][4], lrow[2][4];
    f32x4 accO[2][4] = {};
    #pragma unroll
    for (int mm = 0; mm < 2; ++mm)
        #pragma unroll
        for (int r = 0; r < 4; ++r) { mrow[mm][r] = -3.0e38f; lrow[mm][r] = 0.f; }

    for (int kt = 0; kt < 2048; kt += 64) {
        // issue K / V^T tile loads early (overlap with previous PV)
        int4 kreg[2], vreg[2];
        #pragma unroll
        for (int c = 0; c < 2; ++c) {
            const int idx = c * 256 + tid;
            const int row = idx >> 3, ch = idx & 7;
            kreg[c] = *(const int4*)(Kb + (size_t)(kt + row) * 64 + ch * 8);
            vreg[c] = *(const int4*)(Vb + (size_t)row * 2048 + kt + ch * 8);
        }
        __syncthreads();                       // prev iteration's LDS reads done
        #pragma unroll
        for (int c = 0; c < 2; ++c) {
            const int idx = c * 256 + tid;
            const int row = idx >> 3, ch = idx & 7;
            *(int4*)(Ks + row * 72 + ch * 8) = kreg[c];
            *(int4*)(Vs + row * 72 + ch * 8) = vreg[c];
        }
        __syncthreads();

        // --- QK^T ---
        f32x4 sf[2][4] = {};
        #pragma unroll
        for (int n = 0; n < 4; ++n) {
            const short8 kf0 = *(const short8*)(Ks + (n * 16 + lr) * 72 + lg * 8);
            const short8 kf1 = *(const short8*)(Ks + (n * 16 + lr) * 72 + 32 + lg * 8);
            #pragma unroll
            for (int mm = 0; mm < 2; ++mm) {
                sf[mm][n] = MFMA16(qf[mm][0], kf0, sf[mm][n]);
                sf[mm][n] = MFMA16(qf[mm][1], kf1, sf[mm][n]);
            }
        }

        // --- online softmax (rows: q = w*32+mm*16+lg*4+r; cols: n*16+lr) ---
        float rm[2][4];
        bool need = false;
        #pragma unroll
        for (int mm = 0; mm < 2; ++mm)
            #pragma unroll
            for (int r = 0; r < 4; ++r) {
                float a = fmaxf(fmaxf(sf[mm][0][r], sf[mm][1][r]),
                                fmaxf(sf[mm][2][r], sf[mm][3][r]));
                a = fmaxf(a, __shfl_xor(a, 1));
                a = fmaxf(a, __shfl_xor(a, 2));
                a = fmaxf(a, __shfl_xor(a, 4));
                a = fmaxf(a, __shfl_xor(a, 8));
                rm[mm][r] = a;
                need |= (a > mrow[mm][r] + 8.0f);
            }
        if (__any(need)) {                     // rescale path (rare after warmup)
            #pragma unroll
            for (int mm = 0; mm < 2; ++mm)
                #pragma unroll
                for (int r = 0; r < 4; ++r) {
                    const float mnew = fmaxf(mrow[mm][r], rm[mm][r]);
                    const float resc = __expf(mrow[mm][r] - mnew);
                    lrow[mm][r] *= resc;
                    #pragma unroll
                    for (int n = 0; n < 4; ++n) accO[mm][n][r] *= resc;
                    mrow[mm][r] = mnew;
                }
        }
        unsigned short pb[2][4][4];
        #pragma unroll
        for (int mm = 0; mm < 2; ++mm)
            #pragma unroll
            for (int r = 0; r < 4; ++r) {
                const float m = mrow[mm][r];
                const float p0 = __expf(sf[mm][0][r] - m);
                const float p1 = __expf(sf[mm][1][r] - m);
                const float p2 = __expf(sf[mm][2][r] - m);
                const float p3 = __expf(sf[mm][3][r] - m);
                lrow[mm][r] += p0 + p1 + p2 + p3;   // lane-partial; reduced at end
                pb[mm][r][0] = f2bf(p0); pb[mm][r][1] = f2bf(p1);
                pb[mm][r][2] = f2bf(p2); pb[mm][r][3] = f2bf(p3);
            }

        __syncthreads();                       // QK^T reads of Ks done
        #pragma unroll
        for (int mm = 0; mm < 2; ++mm)
            #pragma unroll
            for (int r = 0; r < 4; ++r)
                #pragma unroll
                for (int n = 0; n < 4; ++n)
                    Qs[(w * 32 + mm * 16 + lg * 4 + r) * 72 + n * 16 + lr] = pb[mm][r][n];
        __syncthreads();                       // P visible

        // --- PV ---
        short8 pf[2][2];
        #pragma unroll
        for (int mm = 0; mm < 2; ++mm)
            #pragma unroll
            for (int c = 0; c < 2; ++c)
                pf[mm][c] = *(const short8*)(Qs + (w * 32 + mm * 16 + lr) * 72 + c * 32 + lg * 8);
        #pragma unroll
        for (int n = 0; n < 4; ++n) {
            const short8 vf0 = *(const short8*)(Vs + (n * 16 + lr) * 72 + lg * 8);
            const short8 vf1 = *(const short8*)(Vs + (n * 16 + lr) * 72 + 32 + lg * 8);
            #pragma unroll
            for (int mm = 0; mm < 2; ++mm) {
                accO[mm][n] = MFMA16(pf[mm][0], vf0, accO[mm][n]);
                accO[mm][n] = MFMA16(pf[mm][1], vf1, accO[mm][n]);
            }
        }
    }

    // final: cross-lane l reduction, normalize, write ctx [B,S,D]
    const int b = bh >> 4, h = bh & 15;
    #pragma unroll
    for (int mm = 0; mm < 2; ++mm)
        #pragma unroll
        for (int r = 0; r < 4; ++r) {
            float ls = lrow[mm][r];
            ls += __shfl_xor(ls, 1);
            ls += __shfl_xor(ls, 2);
            ls += __shfl_xor(ls, 4);
            ls += __shfl_xor(ls, 8);
            const float inv = 1.0f / ls;
            const int srow = q0 + w * 32 + mm * 16 + lg * 4 + r;
            const size_t base = ((size_t)b * 2048 + srow) * 1024 + h * 64;
            #pragma unroll
            for (int n = 0; n < 4; ++n)
                ctx[base + n * 16 + lr] = f2bf(accO[mm][n][r] * inv);
        }
}

// ---------------------------------------------------------------------------
extern "C" void kernel_launch(void* const* d_in, const int* in_sizes, int n_in,
                              void* d_out, int out_size, void* d_ws, size_t ws_size,
                              hipStream_t stream) {
    const float* q   = (const float*)d_in[0];
    const float* k   = (const float*)d_in[1];
    const float* v   = (const float*)d_in[2];
    const float* Wq  = (const float*)d_in[3];
    const float* bq  = (const float*)d_in[4];
    const float* Wk  = (const float*)d_in[5];
    const float* bk  = (const float*)d_in[6];
    const float* Wv  = (const float*)d_in[7];
    const float* bv  = (const float*)d_in[8];
    const float* Wo  = (const float*)d_in[9];
    const float* bo  = (const float*)d_in[10];
    const float* Wad = (const float*)d_in[11];
    const float* bad = (const float*)d_in[12];
    const float* Wau = (const float*)d_in[13];
    const float* bau = (const float*)d_in[14];

    const int M = 4096, D = 1024, AD = 128;
    const size_t SZ = (size_t)M * D;

    char* p = (char*)d_ws;
    size_t off = 0;
    auto alloc = [&](size_t bytes) { void* r = p + off; off = (off + bytes + 255) & ~(size_t)255; return r; };
    unsigned short* xq   = (unsigned short*)alloc(SZ * 2);
    unsigned short* xk   = (unsigned short*)alloc(SZ * 2);
    unsigned short* xv   = (unsigned short*)alloc(SZ * 2);
    unsigned short* Wqb  = (unsigned short*)alloc((size_t)D * D * 2);
    unsigned short* Wkb  = (unsigned short*)alloc((size_t)D * D * 2);
    unsigned short* Wvb  = (unsigned short*)alloc((size_t)D * D * 2);
    unsigned short* Wob  = (unsigned short*)alloc((size_t)D * D * 2);
    unsigned short* Wadb = (unsigned short*)alloc((size_t)AD * D * 2);
    unsigned short* Waub = (unsigned short*)alloc((size_t)D * AD * 2);
    unsigned short* Qh   = (unsigned short*)alloc(SZ * 2);   // [B,H,S,64]
    unsigned short* Kh   = (unsigned short*)alloc(SZ * 2);   // [B,H,S,64]
    unsigned short* Vt   = (unsigned short*)alloc(SZ * 2);   // [B,H,64,S]
    unsigned short* ctx  = (unsigned short*)alloc(SZ * 2);   // [M,D]
    float*          outp = (float*)alloc(SZ * 4);            // O-proj fp32
    unsigned short* outb = (unsigned short*)alloc(SZ * 2);   // O-proj bf16
    unsigned short* a1   = (unsigned short*)alloc((size_t)M * AD * 2);

    CvtJobs j;
    j.src[0] = q;   j.dst[0] = xq;   j.n[0] = (int)SZ;   j.scale[0] = 1.f;
    j.src[1] = k;   j.dst[1] = xk;   j.n[1] = (int)SZ;   j.scale[1] = 1.f;
    j.src[2] = v;   j.dst[2] = xv;   j.n[2] = (int)SZ;   j.scale[2] = 1.f;
    j.src[3] = Wq;  j.dst[3] = Wqb;  j.n[3] = D * D;     j.scale[3] = QSCALE;
    j.src[4] = Wk;  j.dst[4] = Wkb;  j.n[4] = D * D;     j.scale[4] = 1.f;
    j.src[5] = Wv;  j.dst[5] = Wvb;  j.n[5] = D * D;     j.scale[5] = 1.f;
    j.src[6] = Wo;  j.dst[6] = Wob;  j.n[6] = D * D;     j.scale[6] = 1.f;
    j.src[7] = Wad; j.dst[7] = Wadb; j.n[7] = AD * D;    j.scale[7] = 1.f;
    j.src[8] = Wau; j.dst[8] = Waub; j.n[8] = D * AD;    j.scale[8] = 1.f;
    long long total = 3LL * SZ + 4LL * D * D + 2LL * AD * D;
    long long total4 = total / 4;
    convert_kernel<<<dim3((unsigned)((total4 + 255) / 256)), dim3(256), 0, stream>>>(j, total4);

    const dim3 blk(256);
    gemm_bf16<0><<<dim3(M / 128, D / 128), blk, 0, stream>>>(xq, Wqb, bq, Qh, nullptr, M, D, D, QSCALE);
    gemm_bf16<0><<<dim3(M / 128, D / 128), blk, 0, stream>>>(xk, Wkb, bk, Kh, nullptr, M, D, D, 1.f);
    gemm_bf16<1><<<dim3(M / 128, D / 128), blk, 0, stream>>>(xv, Wvb, bv, Vt, nullptr, M, D, D, 1.f);

    attn_mfma<<<dim3(2048 / 128, 32), blk, 0, stream>>>(Qh, Kh, Vt, ctx);

    gemm_bf16<2><<<dim3(M / 128, D / 128), blk, 0, stream>>>(ctx, Wob, bo, outp, outb, M, D, D, 1.f);
    gemm64_gelu<<<dim3(M / 64, AD / 64), blk, 0, stream>>>(outb, Wadb, bad, a1, M, AD, D);
    gemm_bf16<4><<<dim3(M / 128, D / 128), blk, 0, stream>>>(a1, Waub, bau, d_out, outp, M, D, AD, 1.f);
}

// Round 5
// 184.462 us; speedup vs baseline: 6.7594x; 1.4273x over previous
//
#include <hip/hip_runtime.h>
#include <hip/hip_bf16.h>
#include <math.h>

// B=2, S=2048, D=1024, H=16, HD=64, AD=128, M=B*S=4096
typedef __attribute__((ext_vector_type(8))) short short8;
typedef __attribute__((ext_vector_type(4))) float f32x4;

#define MFMA16(a,b,c) __builtin_amdgcn_mfma_f32_16x16x32_bf16((a),(b),(c),0,0,0)

__device__ __forceinline__ unsigned short f2bf(float f){
    union { __hip_bfloat16 b; unsigned short u; } cv;
    cv.b = __float2bfloat16(f);
    return cv.u;
}
__device__ __forceinline__ unsigned pk_bf16(float a, float b){
    unsigned r;
    asm("v_cvt_pk_bf16_f32 %0, %1, %2" : "=v"(r) : "v"(a), "v"(b));
    return r;
}
// 2^x via v_exp_f32 (gfx950 hardware exp2); avoids glibc __exp2f macro clash
__device__ __forceinline__ float ex2(float x){
    return __builtin_amdgcn_exp2f(x);
}

#define GLD_LDS16(g, s) \
    __builtin_amdgcn_global_load_lds((const __attribute__((address_space(1))) void*)(g), \
                                     (__attribute__((address_space(3))) void*)(s), 16, 0, 0)

// 0.125 (1/sqrt(HD)) * log2(e) folded into Wq/bq -> softmax uses exp2
#define QSCALE 0.18033688011112042f
#define DEFER_THR 11.0f

// ---------------------------------------------------------------------------
// fp32 -> bf16 batched conversion (9 tensors) with per-job scale
// ---------------------------------------------------------------------------
struct CvtJobs {
    const float* src[9];
    unsigned short* dst[9];
    float scale[9];
    int n[9];
};

__global__ __launch_bounds__(256)
void convert_kernel(CvtJobs j, long long total4) {
    long long i4 = (long long)blockIdx.x * blockDim.x + threadIdx.x;
    if (i4 >= total4) return;
    long long rem = i4 * 4;
    int job = 0;
    while (job < 9 && rem >= j.n[job]) { rem -= j.n[job]; ++job; }
    if (job >= 9) return;
    const float sc = j.scale[job];
    const float4 v = *(const float4*)(j.src[job] + rem);
    ushort4 o;
    o.x = f2bf(v.x * sc); o.y = f2bf(v.y * sc);
    o.z = f2bf(v.z * sc); o.w = f2bf(v.w * sc);
    *(ushort4*)(j.dst[job] + rem) = o;
}

// ---------------------------------------------------------------------------
// Fused QKV projection. BM=128, BN=64, BK=32; grid (M/128, D/64, 3).
// Staging via global_load_lds with pre-swizzled source (u ^= (row>>1)&3),
// frag reads use the same XOR -> conflict-free (<=2-way).
// z=0,1 -> head layout [b,h,s,64]; z=2 -> transposed [b,h,hd,s] (V).
// ---------------------------------------------------------------------------
struct QKVArgs {
    const unsigned short* A[3];
    const unsigned short* W[3];
    const float* bias[3];
    float bscale[3];
    unsigned short* out[3];
};

__global__ __launch_bounds__(256)
void gemm_qkv(QKVArgs ar, int M, int N, int K)
{
    __shared__ unsigned short As[128 * 32];
    __shared__ unsigned short Bs[64 * 32];

    const int z = blockIdx.z;
    const unsigned short* A = ar.A[z];
    const unsigned short* W = ar.W[z];
    const int tid = threadIdx.x;
    const int w = tid >> 6, l = tid & 63;
    const int lr = l & 15, lg = l >> 4;
    const int m0 = blockIdx.x * 128, n0 = blockIdx.y * 64;
    const int ru = lg ^ ((lr >> 1) & 3);

    f32x4 acc[2][4] = {};

    for (int k0 = 0; k0 < K; k0 += 32) {
        __syncthreads();
        #pragma unroll
        for (int c = 0; c < 2; ++c) {
            const int id = c * 256 + tid;
            const int row = id >> 2, u = id & 3;
            const int su = u ^ ((row >> 1) & 3);
            GLD_LDS16((const char*)A + ((size_t)(m0 + row) * K + k0) * 2 + su * 16,
                      (char*)As + (c * 256 + w * 64) * 16);
        }
        {
            const int row = tid >> 2, u = tid & 3;
            const int su = u ^ ((row >> 1) & 3);
            GLD_LDS16((const char*)W + ((size_t)(n0 + row) * K + k0) * 2 + su * 16,
                      (char*)Bs + (w * 64) * 16);
        }
        __syncthreads();

        short8 af[2], bf[4];
        #pragma unroll
        for (int i = 0; i < 2; ++i)
            af[i] = *(const short8*)((const char*)As + (w * 32 + i * 16 + lr) * 64 + ru * 16);
        #pragma unroll
        for (int j = 0; j < 4; ++j)
            bf[j] = *(const short8*)((const char*)Bs + (j * 16 + lr) * 64 + ru * 16);
        #pragma unroll
        for (int i = 0; i < 2; ++i)
            #pragma unroll
            for (int j = 0; j < 4; ++j)
                acc[i][j] = MFMA16(af[i], bf[j], acc[i][j]);
    }

    const float* bias = ar.bias[z];
    const float bsc = ar.bscale[z];
    unsigned short* out = ar.out[z];
    #pragma unroll
    for (int i = 0; i < 2; ++i)
        #pragma unroll
        for (int j = 0; j < 4; ++j)
            #pragma unroll
            for (int r = 0; r < 4; ++r) {
                const int row = m0 + w * 32 + i * 16 + lg * 4 + r;
                const int col = n0 + j * 16 + lr;
                const float c = acc[i][j][r] + bias[col] * bsc;
                const int b = row >> 11, s = row & 2047, h = col >> 6, hd = col & 63;
                if (z < 2)
                    out[((((size_t)(b * 16 + h)) * 2048 + s) << 6) + hd] = f2bf(c);
                else
                    out[((((size_t)(b * 16 + h)) * 64 + hd) << 11) + s] = f2bf(c);
            }
}

// ---------------------------------------------------------------------------
// Generic GEMM (same geometry). MODE 2: fp32 out0 + bf16 out1 (O-proj).
// MODE 4: + fp32 residual(out1) -> fp32 out0 (adapter up).
// ---------------------------------------------------------------------------
template<int MODE>
__global__ __launch_bounds__(256)
void gemm_bf16(const unsigned short* __restrict__ A,
               const unsigned short* __restrict__ Wt,
               const float* __restrict__ bias,
               void* __restrict__ out0,
               void* __restrict__ out1,
               int M, int N, int K)
{
    __shared__ unsigned short As[128 * 32];
    __shared__ unsigned short Bs[64 * 32];

    const int tid = threadIdx.x;
    const int w = tid >> 6, l = tid & 63;
    const int lr = l & 15, lg = l >> 4;
    const int m0 = blockIdx.x * 128, n0 = blockIdx.y * 64;
    const int ru = lg ^ ((lr >> 1) & 3);

    f32x4 acc[2][4] = {};

    for (int k0 = 0; k0 < K; k0 += 32) {
        __syncthreads();
        #pragma unroll
        for (int c = 0; c < 2; ++c) {
            const int id = c * 256 + tid;
            const int row = id >> 2, u = id & 3;
            const int su = u ^ ((row >> 1) & 3);
            GLD_LDS16((const char*)A + ((size_t)(m0 + row) * K + k0) * 2 + su * 16,
                      (char*)As + (c * 256 + w * 64) * 16);
        }
        {
            const int row = tid >> 2, u = tid & 3;
            const int su = u ^ ((row >> 1) & 3);
            GLD_LDS16((const char*)Wt + ((size_t)(n0 + row) * K + k0) * 2 + su * 16,
                      (char*)Bs + (w * 64) * 16);
        }
        __syncthreads();

        short8 af[2], bf[4];
        #pragma unroll
        for (int i = 0; i < 2; ++i)
            af[i] = *(const short8*)((const char*)As + (w * 32 + i * 16 + lr) * 64 + ru * 16);
        #pragma unroll
        for (int j = 0; j < 4; ++j)
            bf[j] = *(const short8*)((const char*)Bs + (j * 16 + lr) * 64 + ru * 16);
        #pragma unroll
        for (int i = 0; i < 2; ++i)
            #pragma unroll
            for (int j = 0; j < 4; ++j)
                acc[i][j] = MFMA16(af[i], bf[j], acc[i][j]);
    }

    #pragma unroll
    for (int i = 0; i < 2; ++i)
        #pragma unroll
        for (int j = 0; j < 4; ++j)
            #pragma unroll
            for (int r = 0; r < 4; ++r) {
                const int row = m0 + w * 32 + i * 16 + lg * 4 + r;
                const int col = n0 + j * 16 + lr;
                const float c = acc[i][j][r] + bias[col];
                if (MODE == 2) {
                    ((float*)out0)[(size_t)row * N + col] = c;
                    ((unsigned short*)out1)[(size_t)row * N + col] = f2bf(c);
                } else {
                    ((float*)out0)[(size_t)row * N + col] =
                        c + ((const float*)out1)[(size_t)row * N + col];
                }
            }
}

// ---------------------------------------------------------------------------
// 64x64-tile GEMM + exact GELU (adapter down, N=128)
// ---------------------------------------------------------------------------
__global__ __launch_bounds__(256)
void gemm64_gelu(const unsigned short* __restrict__ A,
                 const unsigned short* __restrict__ Wt,
                 const float* __restrict__ bias,
                 unsigned short* __restrict__ out,
                 int M, int N, int K)
{
    __shared__ unsigned short As[64 * 32];
    __shared__ unsigned short Bs[64 * 32];

    const int tid = threadIdx.x;
    const int w = tid >> 6, l = tid & 63;
    const int lr = l & 15, lg = l >> 4;
    const int wr = w >> 1, wc = w & 1;
    const int m0 = blockIdx.x * 64, n0 = blockIdx.y * 64;

    f32x4 acc[2][2] = {};

    for (int k0 = 0; k0 < K; k0 += 32) {
        const int row = tid >> 2, ch = tid & 3;
        __syncthreads();
        GLD_LDS16(A  + (size_t)(m0 + row) * K + k0 + ch * 8, As + (w * 64) * 8);
        GLD_LDS16(Wt + (size_t)(n0 + row) * K + k0 + ch * 8, Bs + (w * 64) * 8);
        __syncthreads();

        short8 af[2], bf[2];
        #pragma unroll
        for (int i = 0; i < 2; ++i)
            af[i] = *(const short8*)(As + ((wr * 32 + i * 16 + lr) * 32 + lg * 8));
        #pragma unroll
        for (int j = 0; j < 2; ++j)
            bf[j] = *(const short8*)(Bs + ((wc * 32 + j * 16 + lr) * 32 + lg * 8));
        #pragma unroll
        for (int i = 0; i < 2; ++i)
            #pragma unroll
            for (int j = 0; j < 2; ++j)
                acc[i][j] = MFMA16(af[i], bf[j], acc[i][j]);
    }

    #pragma unroll
    for (int i = 0; i < 2; ++i)
        #pragma unroll
        for (int j = 0; j < 2; ++j)
            #pragma unroll
            for (int r = 0; r < 4; ++r) {
                const int row = m0 + wr * 32 + i * 16 + lg * 4 + r;
                const int col = n0 + wc * 32 + j * 16 + lr;
                const float c = acc[i][j][r] + bias[col];
                const float g = 0.5f * c * (1.0f + erff(c * 0.70710678118654752f));
                out[(size_t)row * N + col] = f2bf(g);
            }
}

// ---------------------------------------------------------------------------
// Flash attention, swapped-operand MFMA. Qh,Kh: [B,H,S,64]; Vt: [B,H,64,S].
// Block = 128 q-rows (4 waves x 32). KV tile 64, double-buffered K/V via
// global_load_lds with pre-swizzled source (u ^= row&7). S^T fragments ->
// per-q softmax with 2 shfl_xor; P^T stored per-wave [q][k] (swizzled,
// b64 writes) -> read back as A-frag, no barriers on the P path.
// One barrier per KV iter. exp2-domain (scale folded into Q).
// ---------------------------------------------------------------------------
__global__ __launch_bounds__(256)
void attn_mfma(const unsigned short* __restrict__ Qh,
               const unsigned short* __restrict__ Kh,
               const unsigned short* __restrict__ Vt,
               unsigned short* __restrict__ ctx)
{
    __shared__ unsigned short Ks[2][64 * 64];   // [row(seq)][d] swizzled
    __shared__ unsigned short Vs[2][64 * 64];   // [row(d)][k]  swizzled
    __shared__ unsigned short Ps[4][32 * 64];   // per-wave P[q][k] swizzled

    const int tid = threadIdx.x;
    const int w = tid >> 6, l = tid & 63;
    const int lr = l & 15, lg = l >> 4;

    // XCD-chunked bijective swizzle (512 blocks, 8 XCDs -> 64-block chunks)
    const int p = blockIdx.x + blockIdx.y * 16;
    const int id = (p & 7) * 64 + (p >> 3);
    const int q0 = (id & 15) << 7;
    const int bh = id >> 4;

    const unsigned short* Qb = Qh + (size_t)bh * 131072;
    const char* Kb = (const char*)(Kh + (size_t)bh * 131072);
    const char* Vb = (const char*)(Vt + (size_t)bh * 131072);

    // stationary Q fragments straight from global
    short8 qf[2][2];
    #pragma unroll
    for (int mm = 0; mm < 2; ++mm)
        #pragma unroll
        for (int c = 0; c < 2; ++c)
            qf[mm][c] = *(const short8*)(Qb + (size_t)(q0 + w * 32 + mm * 16 + lr) * 64
                                            + c * 32 + lg * 8);

    float mrow[2] = {-1e30f, -1e30f};
    float lrow[2] = {0.f, 0.f};
    f32x4 accO[2][4] = {};   // [mm][n(d)] : q=lg*4+r, d=n*16+lr

    // stage K/V tile kt into buffer bf (pre-swizzled global source)
    auto STAGE = [&](int bf, int kt) {
        #pragma unroll
        for (int c = 0; c < 2; ++c) {
            const int cid = c * 256 + tid;
            const int row = cid >> 3, u = cid & 7;
            const int su = u ^ (row & 7);
            GLD_LDS16(Kb + (size_t)(kt + row) * 128 + su * 16,
                      (char*)&Ks[bf][0] + (c * 256 + w * 64) * 16);
            GLD_LDS16(Vb + (size_t)row * 4096 + (size_t)kt * 2 + su * 16,
                      (char*)&Vs[bf][0] + (c * 256 + w * 64) * 16);
        }
    };

    STAGE(0, 0);
    __syncthreads();

    int cur = 0;
    for (int t = 0; t < 32; ++t) {
        if (t < 31) STAGE(cur ^ 1, (t + 1) * 64);

        const char* Kbuf = (const char*)&Ks[cur][0];
        const char* Vbuf = (const char*)&Vs[cur][0];

        // --- QK^T (swapped): sf[mm][n] = S^T tile, k=n*16+lg*4+r, q=mm*16+lr
        f32x4 sf[2][4] = {};
        #pragma unroll
        for (int n = 0; n < 4; ++n) {
            const int krow = n * 16 + lr;
            const short8 kf0 = *(const short8*)(Kbuf + krow * 128 + ((0 * 4 + lg) ^ (lr & 7)) * 16);
            const short8 kf1 = *(const short8*)(Kbuf + krow * 128 + ((1 * 4 + lg) ^ (lr & 7)) * 16);
            #pragma unroll
            for (int mm = 0; mm < 2; ++mm) {
                sf[mm][n] = MFMA16(kf0, qf[mm][0], sf[mm][n]);
                sf[mm][n] = MFMA16(kf1, qf[mm][1], sf[mm][n]);
            }
        }

        // --- softmax (exp2 domain). Per thread: 16 values per mm, all q=lr.
        float rm[2];
        bool need = false;
        #pragma unroll
        for (int mm = 0; mm < 2; ++mm) {
            float a = fmaxf(fmaxf(fmaxf(sf[mm][0][0], sf[mm][0][1]),
                                  fmaxf(sf[mm][0][2], sf[mm][0][3])),
                            fmaxf(fmaxf(sf[mm][1][0], sf[mm][1][1]),
                                  fmaxf(sf[mm][1][2], sf[mm][1][3])));
            float b = fmaxf(fmaxf(fmaxf(sf[mm][2][0], sf[mm][2][1]),
                                  fmaxf(sf[mm][2][2], sf[mm][2][3])),
                            fmaxf(fmaxf(sf[mm][3][0], sf[mm][3][1]),
                                  fmaxf(sf[mm][3][2], sf[mm][3][3])));
            float r2 = fmaxf(a, b);
            r2 = fmaxf(r2, __shfl_xor(r2, 16));
            r2 = fmaxf(r2, __shfl_xor(r2, 32));
            rm[mm] = r2;
            need |= (r2 > mrow[mm] + DEFER_THR);
        }
        if (__any(need)) {
            #pragma unroll
            for (int mm = 0; mm < 2; ++mm) {
                const float mnew = fmaxf(mrow[mm], rm[mm]);
                const float rsc = ex2(mrow[mm] - mnew);
                lrow[mm] *= rsc;
                mrow[mm] = mnew;
                #pragma unroll
                for (int r = 0; r < 4; ++r) {
                    const float rr = __shfl(rsc, (l & 48) | (lg * 4 + r));
                    #pragma unroll
                    for (int n = 0; n < 4; ++n) accO[mm][n][r] *= rr;
                }
            }
        }
        #pragma unroll
        for (int mm = 0; mm < 2; ++mm) {
            const float m = mrow[mm];
            float ls = lrow[mm];
            char* pbase = (char*)&Ps[w][0] + (mm * 16 + lr) * 128;
            #pragma unroll
            for (int n = 0; n < 4; ++n) {
                const float p0 = ex2(sf[mm][n][0] - m);
                const float p1 = ex2(sf[mm][n][1] - m);
                const float p2 = ex2(sf[mm][n][2] - m);
                const float p3 = ex2(sf[mm][n][3] - m);
                ls += (p0 + p1) + (p2 + p3);
                uint2 pk;
                pk.x = pk_bf16(p0, p1);
                pk.y = pk_bf16(p2, p3);
                *(uint2*)(pbase + (((n * 2 + (lg >> 1)) ^ (lr & 7)) * 16) + (lg & 1) * 8) = pk;
            }
            lrow[mm] = ls;
        }

        // --- PV: read P back as A-frag (same wave wrote it; in-order LDS pipe)
        short8 pf[2][2];
        #pragma unroll
        for (int mm = 0; mm < 2; ++mm) {
            const char* pb = (const char*)&Ps[w][0] + (mm * 16 + lr) * 128;
            pf[mm][0] = *(const short8*)(pb + (((0 * 4 + lg) ^ (lr & 7)) * 16));
            pf[mm][1] = *(const short8*)(pb + (((1 * 4 + lg) ^ (lr & 7)) * 16));
        }
        #pragma unroll
        for (int n = 0; n < 4; ++n) {
            const int drow = n * 16 + lr;
            const short8 vf0 = *(const short8*)(Vbuf + drow * 128 + ((0 * 4 + lg) ^ (lr & 7)) * 16);
            const short8 vf1 = *(const short8*)(Vbuf + drow * 128 + ((1 * 4 + lg) ^ (lr & 7)) * 16);
            #pragma unroll
            for (int mm = 0; mm < 2; ++mm) {
                accO[mm][n] = MFMA16(pf[mm][0], vf0, accO[mm][n]);
                accO[mm][n] = MFMA16(pf[mm][1], vf1, accO[mm][n]);
            }
        }

        __syncthreads();      // next-tile stage complete + this tile's reads done
        cur ^= 1;
    }

    // epilogue: reduce l across lane groups, redistribute, write ctx [B,S,D]
    const int b = bh >> 4, h = bh & 15;
    #pragma unroll
    for (int mm = 0; mm < 2; ++mm) {
        float ls = lrow[mm];
        ls += __shfl_xor(ls, 16);
        ls += __shfl_xor(ls, 32);
        const float inv = 1.0f / ls;
        #pragma unroll
        for (int r = 0; r < 4; ++r) {
            const float vr = __shfl(inv, (l & 48) | (lg * 4 + r));
            const int srow = q0 + w * 32 + mm * 16 + lg * 4 + r;
            const size_t base = ((size_t)b * 2048 + srow) * 1024 + h * 64;
            #pragma unroll
            for (int n = 0; n < 4; ++n)
                ctx[base + n * 16 + lr] = f2bf(accO[mm][n][r] * vr);
        }
    }
}

// ---------------------------------------------------------------------------
extern "C" void kernel_launch(void* const* d_in, const int* in_sizes, int n_in,
                              void* d_out, int out_size, void* d_ws, size_t ws_size,
                              hipStream_t stream) {
    const float* q   = (const float*)d_in[0];
    const float* k   = (const float*)d_in[1];
    const float* v   = (const float*)d_in[2];
    const float* Wq  = (const float*)d_in[3];
    const float* bq  = (const float*)d_in[4];
    const float* Wk  = (const float*)d_in[5];
    const float* bk  = (const float*)d_in[6];
    const float* Wv  = (const float*)d_in[7];
    const float* bv  = (const float*)d_in[8];
    const float* Wo  = (const float*)d_in[9];
    const float* bo  = (const float*)d_in[10];
    const float* Wad = (const float*)d_in[11];
    const float* bad = (const float*)d_in[12];
    const float* Wau = (const float*)d_in[13];
    const float* bau = (const float*)d_in[14];

    const int M = 4096, D = 1024, AD = 128;
    const size_t SZ = (size_t)M * D;

    char* p = (char*)d_ws;
    size_t off = 0;
    auto alloc = [&](size_t bytes) { void* r = p + off; off = (off + bytes + 255) & ~(size_t)255; return r; };
    unsigned short* xq   = (unsigned short*)alloc(SZ * 2);
    unsigned short* xk   = (unsigned short*)alloc(SZ * 2);
    unsigned short* xv   = (unsigned short*)alloc(SZ * 2);
    unsigned short* Wqb  = (unsigned short*)alloc((size_t)D * D * 2);
    unsigned short* Wkb  = (unsigned short*)alloc((size_t)D * D * 2);
    unsigned short* Wvb  = (unsigned short*)alloc((size_t)D * D * 2);
    unsigned short* Wob  = (unsigned short*)alloc((size_t)D * D * 2);
    unsigned short* Wadb = (unsigned short*)alloc((size_t)AD * D * 2);
    unsigned short* Waub = (unsigned short*)alloc((size_t)D * AD * 2);
    unsigned short* Qh   = (unsigned short*)alloc(SZ * 2);   // [B,H,S,64]
    unsigned short* Kh   = (unsigned short*)alloc(SZ * 2);   // [B,H,S,64]
    unsigned short* Vt   = (unsigned short*)alloc(SZ * 2);   // [B,H,64,S]
    unsigned short* ctx  = (unsigned short*)alloc(SZ * 2);   // [M,D]
    float*          outp = (float*)alloc(SZ * 4);            // O-proj fp32
    unsigned short* outb = (unsigned short*)alloc(SZ * 2);   // O-proj bf16
    unsigned short* a1   = (unsigned short*)alloc((size_t)M * AD * 2);

    CvtJobs j;
    j.src[0] = q;   j.dst[0] = xq;   j.n[0] = (int)SZ;   j.scale[0] = 1.f;
    j.src[1] = k;   j.dst[1] = xk;   j.n[1] = (int)SZ;   j.scale[1] = 1.f;
    j.src[2] = v;   j.dst[2] = xv;   j.n[2] = (int)SZ;   j.scale[2] = 1.f;
    j.src[3] = Wq;  j.dst[3] = Wqb;  j.n[3] = D * D;     j.scale[3] = QSCALE;
    j.src[4] = Wk;  j.dst[4] = Wkb;  j.n[4] = D * D;     j.scale[4] = 1.f;
    j.src[5] = Wv;  j.dst[5] = Wvb;  j.n[5] = D * D;     j.scale[5] = 1.f;
    j.src[6] = Wo;  j.dst[6] = Wob;  j.n[6] = D * D;     j.scale[6] = 1.f;
    j.src[7] = Wad; j.dst[7] = Wadb; j.n[7] = AD * D;    j.scale[7] = 1.f;
    j.src[8] = Wau; j.dst[8] = Waub; j.n[8] = D * AD;    j.scale[8] = 1.f;
    long long total = 3LL * SZ + 4LL * D * D + 2LL * AD * D;
    long long total4 = total / 4;
    convert_kernel<<<dim3((unsigned)((total4 + 255) / 256)), dim3(256), 0, stream>>>(j, total4);

    const dim3 blk(256);

    QKVArgs qa;
    qa.A[0] = xq;  qa.A[1] = xk;  qa.A[2] = xv;
    qa.W[0] = Wqb; qa.W[1] = Wkb; qa.W[2] = Wvb;
    qa.bias[0] = bq; qa.bias[1] = bk; qa.bias[2] = bv;
    qa.bscale[0] = QSCALE; qa.bscale[1] = 1.f; qa.bscale[2] = 1.f;
    qa.out[0] = Qh; qa.out[1] = Kh; qa.out[2] = Vt;
    gemm_qkv<<<dim3(M / 128, D / 64, 3), blk, 0, stream>>>(qa, M, D, D);

    attn_mfma<<<dim3(2048 / 128, 32), blk, 0, stream>>>(Qh, Kh, Vt, ctx);

    gemm_bf16<2><<<dim3(M / 128, D / 64), blk, 0, stream>>>(ctx, Wob, bo, outp, outb, M, D, D);
    gemm64_gelu<<<dim3(M / 64, AD / 64), blk, 0, stream>>>(outb, Wadb, bad, a1, M, AD, D);
    gemm_bf16<4><<<dim3(M / 128, D / 64), blk, 0, stream>>>(a1, Waub, bau, d_out, outp, M, D, AD);
}

// Round 6
// 171.440 us; speedup vs baseline: 7.2728x; 1.0760x over previous
//
#include <hip/hip_runtime.h>
#include <hip/hip_bf16.h>
#include <math.h>

// B=2, S=2048, D=1024, H=16, HD=64, AD=128, M=B*S=4096
typedef __attribute__((ext_vector_type(8))) short short8;
typedef __attribute__((ext_vector_type(4))) float f32x4;

#define MFMA16(a,b,c) __builtin_amdgcn_mfma_f32_16x16x32_bf16((a),(b),(c),0,0,0)

__device__ __forceinline__ unsigned short f2bf(float f){
    union { __hip_bfloat16 b; unsigned short u; } cv;
    cv.b = __float2bfloat16(f);
    return cv.u;
}
__device__ __forceinline__ unsigned pk_bf16(float a, float b){
    unsigned r;
    asm("v_cvt_pk_bf16_f32 %0, %1, %2" : "=v"(r) : "v"(a), "v"(b));
    return r;
}
// 2^x via v_exp_f32 (gfx950 hardware exp2)
__device__ __forceinline__ float ex2(float x){
    return __builtin_amdgcn_exp2f(x);
}

#define GLD_LDS16(g, s) \
    __builtin_amdgcn_global_load_lds((const __attribute__((address_space(1))) void*)(g), \
                                     (__attribute__((address_space(3))) void*)(s), 16, 0, 0)

// 0.125 (1/sqrt(HD)) * log2(e) folded into Wq/bq -> softmax uses exp2
#define QSCALE 0.18033688011112042f
#define DEFER_THR 11.0f

// ---------------------------------------------------------------------------
// fp32 -> bf16 batched conversion (9 tensors) with per-job scale
// ---------------------------------------------------------------------------
struct CvtJobs {
    const float* src[9];
    unsigned short* dst[9];
    float scale[9];
    int n[9];
};

__global__ __launch_bounds__(256)
void convert_kernel(CvtJobs j, long long total4) {
    long long i4 = (long long)blockIdx.x * blockDim.x + threadIdx.x;
    if (i4 >= total4) return;
    long long rem = i4 * 4;
    int job = 0;
    while (job < 9 && rem >= j.n[job]) { rem -= j.n[job]; ++job; }
    if (job >= 9) return;
    const float sc = j.scale[job];
    const float4 v = *(const float4*)(j.src[job] + rem);
    ushort4 o;
    o.x = f2bf(v.x * sc); o.y = f2bf(v.y * sc);
    o.z = f2bf(v.z * sc); o.w = f2bf(v.w * sc);
    *(ushort4*)(j.dst[job] + rem) = o;
}

// ---------------------------------------------------------------------------
// Shared 128x128 GEMM main loop (m97 structure + conflict-free XOR swizzle).
// BM=128, BN=128, BK=32; 4 waves, each owns a 64x64 quadrant (wr=w>>1, wc=w&1).
// Staging: global_load_lds 16B with pre-swizzled source (u ^= (row>>1)&3);
// frag reads apply the same XOR -> 0 bank conflicts (measured round 5).
// ---------------------------------------------------------------------------
#define GEMM128_LOOP(Aptr, Bptr)                                                     \
    f32x4 acc[4][4] = {};                                                            \
    for (int k0 = 0; k0 < K; k0 += 32) {                                             \
        __syncthreads();                                                             \
        _Pragma("unroll")                                                            \
        for (int c = 0; c < 2; ++c) {                                                \
            const int id = c * 256 + tid;                                            \
            const int row = id >> 2, u = id & 3;                                     \
            const int su = u ^ ((row >> 1) & 3);                                     \
            GLD_LDS16((const char*)(Aptr) + ((size_t)(m0 + row) * K + k0) * 2 + su * 16, \
                      (char*)As + (c * 256 + w * 64) * 16);                          \
            GLD_LDS16((const char*)(Bptr) + ((size_t)(n0 + row) * K + k0) * 2 + su * 16, \
                      (char*)Bs + (c * 256 + w * 64) * 16);                          \
        }                                                                            \
        __syncthreads();                                                             \
        short8 af[4], bfr[4];                                                        \
        _Pragma("unroll")                                                            \
        for (int i = 0; i < 4; ++i)                                                  \
            af[i] = *(const short8*)((const char*)As + (wr * 64 + i * 16 + lr) * 64 + ru * 16); \
        _Pragma("unroll")                                                            \
        for (int jj = 0; jj < 4; ++jj)                                               \
            bfr[jj] = *(const short8*)((const char*)Bs + (wc * 64 + jj * 16 + lr) * 64 + ru * 16); \
        _Pragma("unroll")                                                            \
        for (int i = 0; i < 4; ++i)                                                  \
            _Pragma("unroll")                                                        \
            for (int jj = 0; jj < 4; ++jj)                                           \
                acc[i][jj] = MFMA16(af[i], bfr[jj], acc[i][jj]);                     \
    }

// ---------------------------------------------------------------------------
// Fused QKV projection. grid (M/128, D/128, 3).
// z=0,1 -> head layout [b,h,s,64]; z=2 -> transposed [b,h,hd,s] (V).
// ---------------------------------------------------------------------------
struct QKVArgs {
    const unsigned short* A[3];
    const unsigned short* W[3];
    const float* bias[3];
    float bscale[3];
    unsigned short* out[3];
};

__global__ __launch_bounds__(256)
void gemm_qkv(QKVArgs ar, int M, int N, int K)
{
    __shared__ unsigned short As[128 * 32];
    __shared__ unsigned short Bs[128 * 32];

    const int z = blockIdx.z;
    const unsigned short* A = ar.A[z];
    const unsigned short* W = ar.W[z];
    const int tid = threadIdx.x;
    const int w = tid >> 6, l = tid & 63;
    const int lr = l & 15, lg = l >> 4;
    const int wr = w >> 1, wc = w & 1;
    const int m0 = blockIdx.x * 128, n0 = blockIdx.y * 128;
    const int ru = lg ^ ((lr >> 1) & 3);

    GEMM128_LOOP(A, W)

    const float* bias = ar.bias[z];
    const float bsc = ar.bscale[z];
    unsigned short* out = ar.out[z];
    #pragma unroll
    for (int i = 0; i < 4; ++i)
        #pragma unroll
        for (int jj = 0; jj < 4; ++jj)
            #pragma unroll
            for (int r = 0; r < 4; ++r) {
                const int row = m0 + wr * 64 + i * 16 + lg * 4 + r;
                const int col = n0 + wc * 64 + jj * 16 + lr;
                const float c = acc[i][jj][r] + bias[col] * bsc;
                const int b = row >> 11, s = row & 2047, h = col >> 6, hd = col & 63;
                if (z < 2)
                    out[((((size_t)(b * 16 + h)) * 2048 + s) << 6) + hd] = f2bf(c);
                else
                    out[((((size_t)(b * 16 + h)) * 64 + hd) << 11) + s] = f2bf(c);
            }
}

// ---------------------------------------------------------------------------
// Generic 128x128 GEMM. MODE 2: fp32 out0 + bf16 out1 (O-proj).
// MODE 4: + fp32 residual(out1) -> fp32 out0 (adapter up).
// ---------------------------------------------------------------------------
template<int MODE>
__global__ __launch_bounds__(256)
void gemm_bf16(const unsigned short* __restrict__ A,
               const unsigned short* __restrict__ Wt,
               const float* __restrict__ bias,
               void* __restrict__ out0,
               void* __restrict__ out1,
               int M, int N, int K)
{
    __shared__ unsigned short As[128 * 32];
    __shared__ unsigned short Bs[128 * 32];

    const int tid = threadIdx.x;
    const int w = tid >> 6, l = tid & 63;
    const int lr = l & 15, lg = l >> 4;
    const int wr = w >> 1, wc = w & 1;
    const int m0 = blockIdx.x * 128, n0 = blockIdx.y * 128;
    const int ru = lg ^ ((lr >> 1) & 3);

    GEMM128_LOOP(A, Wt)

    #pragma unroll
    for (int i = 0; i < 4; ++i)
        #pragma unroll
        for (int jj = 0; jj < 4; ++jj)
            #pragma unroll
            for (int r = 0; r < 4; ++r) {
                const int row = m0 + wr * 64 + i * 16 + lg * 4 + r;
                const int col = n0 + wc * 64 + jj * 16 + lr;
                const float c = acc[i][jj][r] + bias[col];
                if (MODE == 2) {
                    ((float*)out0)[(size_t)row * N + col] = c;
                    ((unsigned short*)out1)[(size_t)row * N + col] = f2bf(c);
                } else {
                    ((float*)out0)[(size_t)row * N + col] =
                        c + ((const float*)out1)[(size_t)row * N + col];
                }
            }
}

// ---------------------------------------------------------------------------
// 64x64-tile GEMM + exact GELU (adapter down, N=128)
// ---------------------------------------------------------------------------
__global__ __launch_bounds__(256)
void gemm64_gelu(const unsigned short* __restrict__ A,
                 const unsigned short* __restrict__ Wt,
                 const float* __restrict__ bias,
                 unsigned short* __restrict__ out,
                 int M, int N, int K)
{
    __shared__ unsigned short As[64 * 32];
    __shared__ unsigned short Bs[64 * 32];

    const int tid = threadIdx.x;
    const int w = tid >> 6, l = tid & 63;
    const int lr = l & 15, lg = l >> 4;
    const int wr = w >> 1, wc = w & 1;
    const int m0 = blockIdx.x * 64, n0 = blockIdx.y * 64;

    f32x4 acc[2][2] = {};

    for (int k0 = 0; k0 < K; k0 += 32) {
        const int row = tid >> 2, ch = tid & 3;
        __syncthreads();
        GLD_LDS16(A  + (size_t)(m0 + row) * K + k0 + ch * 8, As + (w * 64) * 8);
        GLD_LDS16(Wt + (size_t)(n0 + row) * K + k0 + ch * 8, Bs + (w * 64) * 8);
        __syncthreads();

        short8 af[2], bfr[2];
        #pragma unroll
        for (int i = 0; i < 2; ++i)
            af[i] = *(const short8*)(As + ((wr * 32 + i * 16 + lr) * 32 + lg * 8));
        #pragma unroll
        for (int jj = 0; jj < 2; ++jj)
            bfr[jj] = *(const short8*)(Bs + ((wc * 32 + jj * 16 + lr) * 32 + lg * 8));
        #pragma unroll
        for (int i = 0; i < 2; ++i)
            #pragma unroll
            for (int jj = 0; jj < 2; ++jj)
                acc[i][jj] = MFMA16(af[i], bfr[jj], acc[i][jj]);
    }

    #pragma unroll
    for (int i = 0; i < 2; ++i)
        #pragma unroll
        for (int jj = 0; jj < 2; ++jj)
            #pragma unroll
            for (int r = 0; r < 4; ++r) {
                const int row = m0 + wr * 32 + i * 16 + lg * 4 + r;
                const int col = n0 + wc * 32 + jj * 16 + lr;
                const float c = acc[i][jj][r] + bias[col];
                const float g = 0.5f * c * (1.0f + erff(c * 0.70710678118654752f));
                out[(size_t)row * N + col] = f2bf(g);
            }
}

// ---------------------------------------------------------------------------
// Flash attention, swapped-operand MFMA (unchanged from round 5 win).
// ---------------------------------------------------------------------------
__global__ __launch_bounds__(256)
void attn_mfma(const unsigned short* __restrict__ Qh,
               const unsigned short* __restrict__ Kh,
               const unsigned short* __restrict__ Vt,
               unsigned short* __restrict__ ctx)
{
    __shared__ unsigned short Ks[2][64 * 64];   // [row(seq)][d] swizzled
    __shared__ unsigned short Vs[2][64 * 64];   // [row(d)][k]  swizzled
    __shared__ unsigned short Ps[4][32 * 64];   // per-wave P[q][k] swizzled

    const int tid = threadIdx.x;
    const int w = tid >> 6, l = tid & 63;
    const int lr = l & 15, lg = l >> 4;

    // XCD-chunked bijective swizzle (512 blocks, 8 XCDs -> 64-block chunks)
    const int p = blockIdx.x + blockIdx.y * 16;
    const int id = (p & 7) * 64 + (p >> 3);
    const int q0 = (id & 15) << 7;
    const int bh = id >> 4;

    const unsigned short* Qb = Qh + (size_t)bh * 131072;
    const char* Kb = (const char*)(Kh + (size_t)bh * 131072);
    const char* Vb = (const char*)(Vt + (size_t)bh * 131072);

    short8 qf[2][2];
    #pragma unroll
    for (int mm = 0; mm < 2; ++mm)
        #pragma unroll
        for (int c = 0; c < 2; ++c)
            qf[mm][c] = *(const short8*)(Qb + (size_t)(q0 + w * 32 + mm * 16 + lr) * 64
                                            + c * 32 + lg * 8);

    float mrow[2] = {-1e30f, -1e30f};
    float lrow[2] = {0.f, 0.f};
    f32x4 accO[2][4] = {};   // [mm][n(d)] : q=lg*4+r, d=n*16+lr

    auto STAGE = [&](int bf, int kt) {
        #pragma unroll
        for (int c = 0; c < 2; ++c) {
            const int cid = c * 256 + tid;
            const int row = cid >> 3, u = cid & 7;
            const int su = u ^ (row & 7);
            GLD_LDS16(Kb + (size_t)(kt + row) * 128 + su * 16,
                      (char*)&Ks[bf][0] + (c * 256 + w * 64) * 16);
            GLD_LDS16(Vb + (size_t)row * 4096 + (size_t)kt * 2 + su * 16,
                      (char*)&Vs[bf][0] + (c * 256 + w * 64) * 16);
        }
    };

    STAGE(0, 0);
    __syncthreads();

    int cur = 0;
    for (int t = 0; t < 32; ++t) {
        if (t < 31) STAGE(cur ^ 1, (t + 1) * 64);

        const char* Kbuf = (const char*)&Ks[cur][0];
        const char* Vbuf = (const char*)&Vs[cur][0];

        // --- QK^T (swapped): sf[mm][n] = S^T tile, k=n*16+lg*4+r, q=mm*16+lr
        f32x4 sf[2][4] = {};
        #pragma unroll
        for (int n = 0; n < 4; ++n) {
            const int krow = n * 16 + lr;
            const short8 kf0 = *(const short8*)(Kbuf + krow * 128 + ((0 * 4 + lg) ^ (lr & 7)) * 16);
            const short8 kf1 = *(const short8*)(Kbuf + krow * 128 + ((1 * 4 + lg) ^ (lr & 7)) * 16);
            #pragma unroll
            for (int mm = 0; mm < 2; ++mm) {
                sf[mm][n] = MFMA16(kf0, qf[mm][0], sf[mm][n]);
                sf[mm][n] = MFMA16(kf1, qf[mm][1], sf[mm][n]);
            }
        }

        // --- softmax (exp2 domain)
        float rm[2];
        bool need = false;
        #pragma unroll
        for (int mm = 0; mm < 2; ++mm) {
            float a = fmaxf(fmaxf(fmaxf(sf[mm][0][0], sf[mm][0][1]),
                                  fmaxf(sf[mm][0][2], sf[mm][0][3])),
                            fmaxf(fmaxf(sf[mm][1][0], sf[mm][1][1]),
                                  fmaxf(sf[mm][1][2], sf[mm][1][3])));
            float b = fmaxf(fmaxf(fmaxf(sf[mm][2][0], sf[mm][2][1]),
                                  fmaxf(sf[mm][2][2], sf[mm][2][3])),
                            fmaxf(fmaxf(sf[mm][3][0], sf[mm][3][1]),
                                  fmaxf(sf[mm][3][2], sf[mm][3][3])));
            float r2 = fmaxf(a, b);
            r2 = fmaxf(r2, __shfl_xor(r2, 16));
            r2 = fmaxf(r2, __shfl_xor(r2, 32));
            rm[mm] = r2;
            need |= (r2 > mrow[mm] + DEFER_THR);
        }
        if (__any(need)) {
            #pragma unroll
            for (int mm = 0; mm < 2; ++mm) {
                const float mnew = fmaxf(mrow[mm], rm[mm]);
                const float rsc = ex2(mrow[mm] - mnew);
                lrow[mm] *= rsc;
                mrow[mm] = mnew;
                #pragma unroll
                for (int r = 0; r < 4; ++r) {
                    const float rr = __shfl(rsc, (l & 48) | (lg * 4 + r));
                    #pragma unroll
                    for (int n = 0; n < 4; ++n) accO[mm][n][r] *= rr;
                }
            }
        }
        #pragma unroll
        for (int mm = 0; mm < 2; ++mm) {
            const float m = mrow[mm];
            float ls = lrow[mm];
            char* pbase = (char*)&Ps[w][0] + (mm * 16 + lr) * 128;
            #pragma unroll
            for (int n = 0; n < 4; ++n) {
                const float p0 = ex2(sf[mm][n][0] - m);
                const float p1 = ex2(sf[mm][n][1] - m);
                const float p2 = ex2(sf[mm][n][2] - m);
                const float p3 = ex2(sf[mm][n][3] - m);
                ls += (p0 + p1) + (p2 + p3);
                uint2 pk;
                pk.x = pk_bf16(p0, p1);
                pk.y = pk_bf16(p2, p3);
                *(uint2*)(pbase + (((n * 2 + (lg >> 1)) ^ (lr & 7)) * 16) + (lg & 1) * 8) = pk;
            }
            lrow[mm] = ls;
        }

        // --- PV
        short8 pf[2][2];
        #pragma unroll
        for (int mm = 0; mm < 2; ++mm) {
            const char* pb = (const char*)&Ps[w][0] + (mm * 16 + lr) * 128;
            pf[mm][0] = *(const short8*)(pb + (((0 * 4 + lg) ^ (lr & 7)) * 16));
            pf[mm][1] = *(const short8*)(pb + (((1 * 4 + lg) ^ (lr & 7)) * 16));
        }
        #pragma unroll
        for (int n = 0; n < 4; ++n) {
            const int drow = n * 16 + lr;
            const short8 vf0 = *(const short8*)(Vbuf + drow * 128 + ((0 * 4 + lg) ^ (lr & 7)) * 16);
            const short8 vf1 = *(const short8*)(Vbuf + drow * 128 + ((1 * 4 + lg) ^ (lr & 7)) * 16);
            #pragma unroll
            for (int mm = 0; mm < 2; ++mm) {
                accO[mm][n] = MFMA16(pf[mm][0], vf0, accO[mm][n]);
                accO[mm][n] = MFMA16(pf[mm][1], vf1, accO[mm][n]);
            }
        }

        __syncthreads();
        cur ^= 1;
    }

    // epilogue
    const int b = bh >> 4, h = bh & 15;
    #pragma unroll
    for (int mm = 0; mm < 2; ++mm) {
        float ls = lrow[mm];
        ls += __shfl_xor(ls, 16);
        ls += __shfl_xor(ls, 32);
        const float inv = 1.0f / ls;
        #pragma unroll
        for (int r = 0; r < 4; ++r) {
            const float vr = __shfl(inv, (l & 48) | (lg * 4 + r));
            const int srow = q0 + w * 32 + mm * 16 + lg * 4 + r;
            const size_t base = ((size_t)b * 2048 + srow) * 1024 + h * 64;
            #pragma unroll
            for (int n = 0; n < 4; ++n)
                ctx[base + n * 16 + lr] = f2bf(accO[mm][n][r] * vr);
        }
    }
}

// ---------------------------------------------------------------------------
extern "C" void kernel_launch(void* const* d_in, const int* in_sizes, int n_in,
                              void* d_out, int out_size, void* d_ws, size_t ws_size,
                              hipStream_t stream) {
    const float* q   = (const float*)d_in[0];
    const float* k   = (const float*)d_in[1];
    const float* v   = (const float*)d_in[2];
    const float* Wq  = (const float*)d_in[3];
    const float* bq  = (const float*)d_in[4];
    const float* Wk  = (const float*)d_in[5];
    const float* bk  = (const float*)d_in[6];
    const float* Wv  = (const float*)d_in[7];
    const float* bv  = (const float*)d_in[8];
    const float* Wo  = (const float*)d_in[9];
    const float* bo  = (const float*)d_in[10];
    const float* Wad = (const float*)d_in[11];
    const float* bad = (const float*)d_in[12];
    const float* Wau = (const float*)d_in[13];
    const float* bau = (const float*)d_in[14];

    const int M = 4096, D = 1024, AD = 128;
    const size_t SZ = (size_t)M * D;

    char* p = (char*)d_ws;
    size_t off = 0;
    auto alloc = [&](size_t bytes) { void* r = p + off; off = (off + bytes + 255) & ~(size_t)255; return r; };
    unsigned short* xq   = (unsigned short*)alloc(SZ * 2);
    unsigned short* xk   = (unsigned short*)alloc(SZ * 2);
    unsigned short* xv   = (unsigned short*)alloc(SZ * 2);
    unsigned short* Wqb  = (unsigned short*)alloc((size_t)D * D * 2);
    unsigned short* Wkb  = (unsigned short*)alloc((size_t)D * D * 2);
    unsigned short* Wvb  = (unsigned short*)alloc((size_t)D * D * 2);
    unsigned short* Wob  = (unsigned short*)alloc((size_t)D * D * 2);
    unsigned short* Wadb = (unsigned short*)alloc((size_t)AD * D * 2);
    unsigned short* Waub = (unsigned short*)alloc((size_t)D * AD * 2);
    unsigned short* Qh   = (unsigned short*)alloc(SZ * 2);   // [B,H,S,64]
    unsigned short* Kh   = (unsigned short*)alloc(SZ * 2);   // [B,H,S,64]
    unsigned short* Vt   = (unsigned short*)alloc(SZ * 2);   // [B,H,64,S]
    unsigned short* ctx  = (unsigned short*)alloc(SZ * 2);   // [M,D]
    float*          outp = (float*)alloc(SZ * 4);            // O-proj fp32
    unsigned short* outb = (unsigned short*)alloc(SZ * 2);   // O-proj bf16
    unsigned short* a1   = (unsigned short*)alloc((size_t)M * AD * 2);

    CvtJobs j;
    j.src[0] = q;   j.dst[0] = xq;   j.n[0] = (int)SZ;   j.scale[0] = 1.f;
    j.src[1] = k;   j.dst[1] = xk;   j.n[1] = (int)SZ;   j.scale[1] = 1.f;
    j.src[2] = v;   j.dst[2] = xv;   j.n[2] = (int)SZ;   j.scale[2] = 1.f;
    j.src[3] = Wq;  j.dst[3] = Wqb;  j.n[3] = D * D;     j.scale[3] = QSCALE;
    j.src[4] = Wk;  j.dst[4] = Wkb;  j.n[4] = D * D;     j.scale[4] = 1.f;
    j.src[5] = Wv;  j.dst[5] = Wvb;  j.n[5] = D * D;     j.scale[5] = 1.f;
    j.src[6] = Wo;  j.dst[6] = Wob;  j.n[6] = D * D;     j.scale[6] = 1.f;
    j.src[7] = Wad; j.dst[7] = Wadb; j.n[7] = AD * D;    j.scale[7] = 1.f;
    j.src[8] = Wau; j.dst[8] = Waub; j.n[8] = D * AD;    j.scale[8] = 1.f;
    long long total = 3LL * SZ + 4LL * D * D + 2LL * AD * D;
    long long total4 = total / 4;
    convert_kernel<<<dim3((unsigned)((total4 + 255) / 256)), dim3(256), 0, stream>>>(j, total4);

    const dim3 blk(256);

    QKVArgs qa;
    qa.A[0] = xq;  qa.A[1] = xk;  qa.A[2] = xv;
    qa.W[0] = Wqb; qa.W[1] = Wkb; qa.W[2] = Wvb;
    qa.bias[0] = bq; qa.bias[1] = bk; qa.bias[2] = bv;
    qa.bscale[0] = QSCALE; qa.bscale[1] = 1.f; qa.bscale[2] = 1.f;
    qa.out[0] = Qh; qa.out[1] = Kh; qa.out[2] = Vt;
    gemm_qkv<<<dim3(M / 128, D / 128, 3), blk, 0, stream>>>(qa, M, D, D);

    attn_mfma<<<dim3(2048 / 128, 32), blk, 0, stream>>>(Qh, Kh, Vt, ctx);

    gemm_bf16<2><<<dim3(M / 128, D / 128), blk, 0, stream>>>(ctx, Wob, bo, outp, outb, M, D, D);
    gemm64_gelu<<<dim3(M / 64, AD / 64), blk, 0, stream>>>(outb, Wadb, bad, a1, M, AD, D);
    gemm_bf16<4><<<dim3(M / 128, D / 128), blk, 0, stream>>>(a1, Waub, bau, d_out, outp, M, D, AD);
}